// Round 1
// baseline (376.151 us; speedup 1.0000x reference)
//
#include <hip/hip_runtime.h>

typedef unsigned short u16;
typedef __attribute__((ext_vector_type(8))) __bf16 bf16x8;
typedef __attribute__((ext_vector_type(4))) float f32x4;
typedef __attribute__((ext_vector_type(8))) u16 u16x8;

#define T_SEQ 2048
#define DIM   1024
#define HDIM  64
#define WIN   128

__device__ __forceinline__ u16 f2bf(float f) {
  union { float f; unsigned u; } v; v.f = f;
  unsigned r = v.u + 0x7fffu + ((v.u >> 16) & 1u);  // RNE
  return (u16)(r >> 16);
}

// ---------------- fp32 -> bf16 convert (vectorized, 8/thread) ----------------
__global__ __launch_bounds__(256) void cvt_bf16(const float* __restrict__ s,
                                                u16* __restrict__ d, int n8) {
  int i = blockIdx.x * 256 + threadIdx.x;
  if (i >= n8) return;
  const float4* s4 = (const float4*)s;
  float4 a = s4[i * 2], b = s4[i * 2 + 1];
  u16x8 r;
  r[0] = f2bf(a.x); r[1] = f2bf(a.y); r[2] = f2bf(a.z); r[3] = f2bf(a.w);
  r[4] = f2bf(b.x); r[5] = f2bf(b.y); r[6] = f2bf(b.z); r[7] = f2bf(b.w);
  *(u16x8*)(d + i * 8) = r;
}

// ---------------- C = A @ B^T GEMM, bf16 in, OUT_T out -----------------------
// M=4096 (rows of A), N=1024 per matrix, K=1024, all strides 1024.
// 128x128 tile, BK=64, 256 threads (4 waves 2x2), global_load_lds width 16.
template <typename OUT_T>
__global__ __launch_bounds__(256) void gemm_bt(
    const u16* __restrict__ A, const u16* __restrict__ B0,
    const u16* __restrict__ B1, const u16* __restrict__ B2,
    OUT_T* __restrict__ C0, OUT_T* __restrict__ C1, OUT_T* __restrict__ C2) {
  __shared__ u16 As[128 * 64];
  __shared__ u16 Bs[128 * 64];
  const int tid = threadIdx.x;
  const int lane = tid & 63;
  const int wid = tid >> 6;
  const int bm = blockIdx.x;
  const int mat = blockIdx.y >> 3, nb = blockIdx.y & 7;
  const u16* Bmat = (mat == 0) ? B0 : ((mat == 1) ? B1 : B2);
  OUT_T* Cmat = (mat == 0) ? C0 : ((mat == 1) ? C1 : C2);
  const u16* Ab = A + (size_t)bm * 128 * DIM;
  const u16* Bb = Bmat + (size_t)nb * 128 * DIM;
  const int wr = wid >> 1, wc = wid & 1;
  const int c15 = lane & 15, g = lane >> 4;

  f32x4 acc[4][4];
#pragma unroll
  for (int m = 0; m < 4; ++m)
#pragma unroll
    for (int n = 0; n < 4; ++n) acc[m][n] = (f32x4){0.f, 0.f, 0.f, 0.f};

  const int srow = lane >> 3;       // 0..7 within the wave's 8-row chunk
  const int scol = (lane & 7) * 8;  // 0..56

  for (int k0 = 0; k0 < DIM; k0 += 64) {
#pragma unroll
    for (int i = 0; i < 4; ++i) {
      const int r = i * 32 + wid * 8;
      __builtin_amdgcn_global_load_lds(
          (const __attribute__((address_space(1))) void*)(Ab + (size_t)(r + srow) * DIM + k0 + scol),
          (__attribute__((address_space(3))) void*)(As + r * 64), 16, 0, 0);
      __builtin_amdgcn_global_load_lds(
          (const __attribute__((address_space(1))) void*)(Bb + (size_t)(r + srow) * DIM + k0 + scol),
          (__attribute__((address_space(3))) void*)(Bs + r * 64), 16, 0, 0);
    }
    __syncthreads();
#pragma unroll
    for (int kk = 0; kk < 2; ++kk) {
      bf16x8 af[4], bfr[4];
#pragma unroll
      for (int m = 0; m < 4; ++m)
        af[m] = *(const bf16x8*)(As + (wr * 64 + m * 16 + c15) * 64 + kk * 32 + g * 8);
#pragma unroll
      for (int n = 0; n < 4; ++n)
        bfr[n] = *(const bf16x8*)(Bs + (wc * 64 + n * 16 + c15) * 64 + kk * 32 + g * 8);
#pragma unroll
      for (int m = 0; m < 4; ++m)
#pragma unroll
        for (int n = 0; n < 4; ++n)
          acc[m][n] = __builtin_amdgcn_mfma_f32_16x16x32_bf16(af[m], bfr[n], acc[m][n], 0, 0, 0);
    }
    __syncthreads();
  }
  // epilogue: C/D layout col=lane&15, row=(lane>>4)*4+j  [m89/m91]
#pragma unroll
  for (int m = 0; m < 4; ++m) {
    const int row0 = bm * 128 + wr * 64 + m * 16 + g * 4;
#pragma unroll
    for (int n = 0; n < 4; ++n) {
      const int col = nb * 128 + wc * 64 + n * 16 + c15;
#pragma unroll
      for (int j = 0; j < 4; ++j) {
        const size_t idx = (size_t)(row0 + j) * DIM + col;
        if constexpr (sizeof(OUT_T) == 2) Cmat[idx] = f2bf(acc[m][n][j]);
        else Cmat[idx] = acc[m][n][j];
      }
    }
  }
}

// ---------------- sparse flash attention ------------------------------------
// V-transpose scatter with per-lane-rotated write order (kills the 16-way
// LDS bank conflict; template S keeps vector indices compile-time).
template <int S>
__device__ __forceinline__ void vt_scatter(u16* __restrict__ Vt, const u16x8& vv,
                                           int sc, int sr) {
#pragma unroll
  for (int i = 0; i < 8; ++i) {
    const int e = (i + S) & 7;
    Vt[(sc + e) * 40 + sr] = vv[e];
  }
}

__global__ __launch_bounds__(256) void sparse_attn(
    const u16* __restrict__ Q, const u16* __restrict__ K,
    const u16* __restrict__ V, u16* __restrict__ AO) {
  __shared__ u16 Ks[32 * 72];      // [32 keys][64 hd] pitch 72 (pad: 2-way reads)
  __shared__ u16 Vt[64 * 40];      // [64 hd][32 keys] pitch 40
  __shared__ u16 Pl[4][16 * 40];   // per-wave P [16 q][32 keys] pitch 40

  const int tid = threadIdx.x;
  const int lane = tid & 63;
  const int wid = tid >> 6;
  const int c15 = lane & 15;
  const int g = lane >> 4;
  const int q0 = blockIdx.x * 64;
  const size_t hb = (size_t)blockIdx.z * T_SEQ * DIM + (size_t)blockIdx.y * HDIM;

  // Q fragments (wave owns 16 q-rows): A-frag row = lane&15, k = (lane>>4)*8+e
  bf16x8 qf0, qf1;
  {
    const u16* qp = Q + hb + (size_t)(q0 + wid * 16 + c15) * DIM + g * 8;
    qf0 = *(const bf16x8*)qp;
    qf1 = *(const bf16x8*)(qp + 32);
  }

  float mrun[4], lrun[4], corr[4];
  f32x4 ao[4];
#pragma unroll
  for (int j = 0; j < 4; ++j) { mrun[j] = -1e30f; lrun[j] = 0.f; }
#pragma unroll
  for (int c = 0; c < 4; ++c) ao[c] = (f32x4){0.f, 0.f, 0.f, 0.f};

  const int klo = (q0 > WIN) ? (q0 - WIN) : 0;
  int khi = (q0 == 0) ? T_SEQ : (q0 + 64 + WIN);
  if (khi > T_SEQ) khi = T_SEQ;

  const int sr = tid >> 3;         // staging: key row 0..31
  const int sc = (tid & 7) * 8;    // staging: hd col group

  for (int ti = (klo > 0) ? -1 : 0;; ++ti) {
    const int kt = (ti < 0) ? 0 : (klo + ti * 32);  // ti==-1: global-token tile
    if (kt >= khi) break;
    // ---- stage K [32][72] and V^T [64][40] ----
    {
      const u16* kp = K + hb + (size_t)(kt + sr) * DIM + sc;
      *(u16x8*)(Ks + sr * 72 + sc) = *(const u16x8*)kp;
      const u16x8 vv = *(const u16x8*)(V + hb + (size_t)(kt + sr) * DIM + sc);
      switch (tid & 7) {
        case 0: vt_scatter<0>(Vt, vv, sc, sr); break;
        case 1: vt_scatter<1>(Vt, vv, sc, sr); break;
        case 2: vt_scatter<2>(Vt, vv, sc, sr); break;
        case 3: vt_scatter<3>(Vt, vv, sc, sr); break;
        case 4: vt_scatter<4>(Vt, vv, sc, sr); break;
        case 5: vt_scatter<5>(Vt, vv, sc, sr); break;
        case 6: vt_scatter<6>(Vt, vv, sc, sr); break;
        case 7: vt_scatter<7>(Vt, vv, sc, sr); break;
      }
    }
    __syncthreads();

    // ---- S = Q K^T (two 16-key groups) ----
    f32x4 s0 = {0.f, 0.f, 0.f, 0.f}, s1 = {0.f, 0.f, 0.f, 0.f};
    {
      bf16x8 k00 = *(const bf16x8*)(Ks + c15 * 72 + g * 8);
      bf16x8 k01 = *(const bf16x8*)(Ks + c15 * 72 + 32 + g * 8);
      bf16x8 k10 = *(const bf16x8*)(Ks + (16 + c15) * 72 + g * 8);
      bf16x8 k11 = *(const bf16x8*)(Ks + (16 + c15) * 72 + 32 + g * 8);
      s0 = __builtin_amdgcn_mfma_f32_16x16x32_bf16(qf0, k00, s0, 0, 0, 0);
      s0 = __builtin_amdgcn_mfma_f32_16x16x32_bf16(qf1, k01, s0, 0, 0, 0);
      s1 = __builtin_amdgcn_mfma_f32_16x16x32_bf16(qf0, k10, s1, 0, 0, 0);
      s1 = __builtin_amdgcn_mfma_f32_16x16x32_bf16(qf1, k11, s1, 0, 0, 0);
    }
    // ---- mask + online softmax (rows live across 16-lane groups) ----
#pragma unroll
    for (int j = 0; j < 4; ++j) {
      const int qg = q0 + wid * 16 + g * 4 + j;
      const int kg0 = kt + c15;
      const int kg1 = kg0 + 16;
      float v0 = s0[j] * 0.125f;
      float v1 = s1[j] * 0.125f;
      const int d0 = qg - kg0, d1 = qg - kg1;
      if (!((kg0 == 0) || (qg == 0) || (d0 <= WIN && d0 >= -WIN))) v0 = -1e30f;
      if (!((qg == 0) || (d1 <= WIN && d1 >= -WIN))) v1 = -1e30f;  // kg1>=16, never global
      float rmax = fmaxf(v0, v1);
      rmax = fmaxf(rmax, __shfl_xor(rmax, 1));
      rmax = fmaxf(rmax, __shfl_xor(rmax, 2));
      rmax = fmaxf(rmax, __shfl_xor(rmax, 4));
      rmax = fmaxf(rmax, __shfl_xor(rmax, 8));
      const float mnew = fmaxf(mrun[j], rmax);
      const float p0 = __expf(v0 - mnew);
      const float p1 = __expf(v1 - mnew);
      float rs = p0 + p1;
      rs += __shfl_xor(rs, 1);
      rs += __shfl_xor(rs, 2);
      rs += __shfl_xor(rs, 4);
      rs += __shfl_xor(rs, 8);
      const float cr = __expf(mrun[j] - mnew);
      lrun[j] = lrun[j] * cr + rs;
      mrun[j] = mnew;
      corr[j] = cr;
      const int prow = g * 4 + j;
      Pl[wid][prow * 40 + c15] = f2bf(p0);
      Pl[wid][prow * 40 + 16 + c15] = f2bf(p1);
    }
#pragma unroll
    for (int c = 0; c < 4; ++c)
#pragma unroll
      for (int j = 0; j < 4; ++j) ao[c][j] *= corr[j];

    // wave-internal ds_write -> ds_read ordering
    asm volatile("s_waitcnt lgkmcnt(0)" ::: "memory");

    // ---- O += P @ V ----
    const bf16x8 pa = *(const bf16x8*)(&Pl[wid][c15 * 40 + g * 8]);
#pragma unroll
    for (int c = 0; c < 4; ++c) {
      bf16x8 vf = *(const bf16x8*)(Vt + (c * 16 + c15) * 40 + g * 8);
      ao[c] = __builtin_amdgcn_mfma_f32_16x16x32_bf16(pa, vf, ao[c], 0, 0, 0);
    }
    __syncthreads();
  }
  // ---- writeout (bf16 into AO) ----
#pragma unroll
  for (int j = 0; j < 4; ++j) {
    const int qrow = q0 + wid * 16 + g * 4 + j;
    const float inv = 1.0f / lrun[j];
#pragma unroll
    for (int c = 0; c < 4; ++c)
      AO[hb + (size_t)qrow * DIM + c * 16 + c15] = f2bf(ao[c][j] * inv);
  }
}

// ---------------- launch -----------------------------------------------------
extern "C" void kernel_launch(void* const* d_in, const int* in_sizes, int n_in,
                              void* d_out, int out_size, void* d_ws, size_t ws_size,
                              hipStream_t stream) {
  const float* x  = (const float*)d_in[0];
  const float* Wq = (const float*)d_in[1];
  const float* Wk = (const float*)d_in[2];
  const float* Wv = (const float*)d_in[3];
  const float* Wo = (const float*)d_in[4];
  float* out = (float*)d_out;

  const int XN = 2 * T_SEQ * DIM;  // 4194304
  const int WN = DIM * DIM;        // 1048576

  u16* ws  = (u16*)d_ws;
  u16* xb  = ws;                 // [4096][1024] bf16 x; reused as AO after QKV
  u16* Wqb = ws + (size_t)XN;
  u16* Wkb = Wqb + WN;
  u16* Wvb = Wkb + WN;
  u16* Wob = Wvb + WN;
  u16* Qb  = Wob + WN;
  u16* Kb  = Qb + (size_t)XN;
  u16* Vb  = Kb + (size_t)XN;
  // total: 20M u16 = 40 MB

  cvt_bf16<<<XN / 8 / 256, 256, 0, stream>>>(x, xb, XN / 8);
  cvt_bf16<<<WN / 8 / 256, 256, 0, stream>>>(Wq, Wqb, WN / 8);
  cvt_bf16<<<WN / 8 / 256, 256, 0, stream>>>(Wk, Wkb, WN / 8);
  cvt_bf16<<<WN / 8 / 256, 256, 0, stream>>>(Wv, Wvb, WN / 8);
  cvt_bf16<<<WN / 8 / 256, 256, 0, stream>>>(Wo, Wob, WN / 8);

  // fused QKV projection: grid.y = 3 mats x 8 n-blocks
  gemm_bt<u16><<<dim3(32, 24), 256, 0, stream>>>(xb, Wqb, Wkb, Wvb, Qb, Kb, Vb);

  // sparse attention: AO overwrites xb (x no longer needed)
  sparse_attn<<<dim3(T_SEQ / 64, 16, 2), 256, 0, stream>>>(Qb, Kb, Vb, xb);

  // output projection -> fp32 d_out
  gemm_bt<float><<<dim3(32, 8), 256, 0, stream>>>(xb, Wob, Wob, Wob, out, out, out);
}

// Round 2
// 178.097 us; speedup vs baseline: 2.1121x; 2.1121x over previous
//
#include <hip/hip_runtime.h>

typedef unsigned short u16;
typedef __attribute__((ext_vector_type(8))) __bf16 bf16x8;
typedef __attribute__((ext_vector_type(4))) float f32x4;
typedef __attribute__((ext_vector_type(8))) u16 u16x8;

#define T_SEQ 2048
#define DIM   1024
#define HDIM  64
#define WIN   128

__device__ __forceinline__ u16 f2bf(float f) {
  union { float f; unsigned u; } v; v.f = f;
  unsigned r = v.u + 0x7fffu + ((v.u >> 16) & 1u);  // RNE
  return (u16)(r >> 16);
}
__device__ __forceinline__ float bf2f(u16 u) {
  union { unsigned u; float f; } v; v.u = ((unsigned)u) << 16; return v.f;
}

// ---------------- fp32 -> bf16 convert (vectorized, 8/thread) ----------------
__global__ __launch_bounds__(256) void cvt_bf16(const float* __restrict__ s,
                                                u16* __restrict__ d, int n8) {
  int i = blockIdx.x * 256 + threadIdx.x;
  if (i >= n8) return;
  const float4* s4 = (const float4*)s;
  float4 a = s4[i * 2], b = s4[i * 2 + 1];
  u16x8 r;
  r[0] = f2bf(a.x); r[1] = f2bf(a.y); r[2] = f2bf(a.z); r[3] = f2bf(a.w);
  r[4] = f2bf(b.x); r[5] = f2bf(b.y); r[6] = f2bf(b.z); r[7] = f2bf(b.w);
  *(u16x8*)(d + i * 8) = r;
}

// ---------------- C = A @ B^T GEMM, bf16 in, OUT_T out -----------------------
template <typename OUT_T>
__global__ __launch_bounds__(256) void gemm_bt(
    const u16* __restrict__ A, const u16* __restrict__ B0,
    const u16* __restrict__ B1, const u16* __restrict__ B2,
    OUT_T* __restrict__ C0, OUT_T* __restrict__ C1, OUT_T* __restrict__ C2) {
  __shared__ u16 As[128 * 64];
  __shared__ u16 Bs[128 * 64];
  const int tid = threadIdx.x;
  const int lane = tid & 63;
  const int wid = tid >> 6;
  const int bm = blockIdx.x;
  const int mat = blockIdx.y >> 3, nb = blockIdx.y & 7;
  const u16* Bmat = (mat == 0) ? B0 : ((mat == 1) ? B1 : B2);
  OUT_T* Cmat = (mat == 0) ? C0 : ((mat == 1) ? C1 : C2);
  const u16* Ab = A + (size_t)bm * 128 * DIM;
  const u16* Bb = Bmat + (size_t)nb * 128 * DIM;
  const int wr = wid >> 1, wc = wid & 1;
  const int c15 = lane & 15, g = lane >> 4;

  f32x4 acc[4][4];
#pragma unroll
  for (int m = 0; m < 4; ++m)
#pragma unroll
    for (int n = 0; n < 4; ++n) acc[m][n] = (f32x4){0.f, 0.f, 0.f, 0.f};

  const int srow = lane >> 3;
  const int scol = (lane & 7) * 8;

  for (int k0 = 0; k0 < DIM; k0 += 64) {
#pragma unroll
    for (int i = 0; i < 4; ++i) {
      const int r = i * 32 + wid * 8;
      __builtin_amdgcn_global_load_lds(
          (const __attribute__((address_space(1))) void*)(Ab + (size_t)(r + srow) * DIM + k0 + scol),
          (__attribute__((address_space(3))) void*)(As + r * 64), 16, 0, 0);
      __builtin_amdgcn_global_load_lds(
          (const __attribute__((address_space(1))) void*)(Bb + (size_t)(r + srow) * DIM + k0 + scol),
          (__attribute__((address_space(3))) void*)(Bs + r * 64), 16, 0, 0);
    }
    __syncthreads();
#pragma unroll
    for (int kk = 0; kk < 2; ++kk) {
      bf16x8 af[4], bfr[4];
#pragma unroll
      for (int m = 0; m < 4; ++m)
        af[m] = *(const bf16x8*)(As + (wr * 64 + m * 16 + c15) * 64 + kk * 32 + g * 8);
#pragma unroll
      for (int n = 0; n < 4; ++n)
        bfr[n] = *(const bf16x8*)(Bs + (wc * 64 + n * 16 + c15) * 64 + kk * 32 + g * 8);
#pragma unroll
      for (int m = 0; m < 4; ++m)
#pragma unroll
        for (int n = 0; n < 4; ++n)
          acc[m][n] = __builtin_amdgcn_mfma_f32_16x16x32_bf16(af[m], bfr[n], acc[m][n], 0, 0, 0);
    }
    __syncthreads();
  }
#pragma unroll
  for (int m = 0; m < 4; ++m) {
    const int row0 = bm * 128 + wr * 64 + m * 16 + g * 4;
#pragma unroll
    for (int n = 0; n < 4; ++n) {
      const int col = nb * 128 + wc * 64 + n * 16 + c15;
#pragma unroll
      for (int j = 0; j < 4; ++j) {
        const size_t idx = (size_t)(row0 + j) * DIM + col;
        if constexpr (sizeof(OUT_T) == 2) Cmat[idx] = f2bf(acc[m][n][j]);
        else Cmat[idx] = acc[m][n][j];
      }
    }
  }
}

// ---------------- sparse flash attention (windowed rows only) ----------------
template <int S>
__device__ __forceinline__ void vt_scatter(u16* __restrict__ Vt, const u16x8& vv,
                                           int sc, int sr) {
#pragma unroll
  for (int i = 0; i < 8; ++i) {
    const int e = (i + S) & 7;
    Vt[(sc + e) * 40 + sr] = vv[e];
  }
}
__device__ __forceinline__ void vt_dispatch(u16* __restrict__ Vt, const u16x8& vv,
                                            int sel, int sc, int sr) {
  switch (sel) {
    case 0: vt_scatter<0>(Vt, vv, sc, sr); break;
    case 1: vt_scatter<1>(Vt, vv, sc, sr); break;
    case 2: vt_scatter<2>(Vt, vv, sc, sr); break;
    case 3: vt_scatter<3>(Vt, vv, sc, sr); break;
    case 4: vt_scatter<4>(Vt, vv, sc, sr); break;
    case 5: vt_scatter<5>(Vt, vv, sc, sr); break;
    case 6: vt_scatter<6>(Vt, vv, sc, sr); break;
    case 7: vt_scatter<7>(Vt, vv, sc, sr); break;
  }
}

__global__ __launch_bounds__(256) void sparse_attn(
    const u16* __restrict__ Q, const u16* __restrict__ K,
    const u16* __restrict__ V, u16* __restrict__ AO) {
  __shared__ u16 Ks[32 * 72];
  __shared__ u16 Vt[64 * 40];
  __shared__ u16 Pl[4][16 * 40];

  const int tid = threadIdx.x;
  const int lane = tid & 63;
  const int wid = tid >> 6;
  const int c15 = lane & 15;
  const int g = lane >> 4;
  const int q0 = blockIdx.x * 64;
  const size_t hb = (size_t)blockIdx.z * T_SEQ * DIM + (size_t)blockIdx.y * HDIM;

  bf16x8 qf0, qf1;
  {
    const u16* qp = Q + hb + (size_t)(q0 + wid * 16 + c15) * DIM + g * 8;
    qf0 = *(const bf16x8*)qp;
    qf1 = *(const bf16x8*)(qp + 32);
  }

  float mrun[4], lrun[4], corr[4];
  f32x4 ao[4];
#pragma unroll
  for (int j = 0; j < 4; ++j) { mrun[j] = -1e30f; lrun[j] = 0.f; }
#pragma unroll
  for (int c = 0; c < 4; ++c) ao[c] = (f32x4){0.f, 0.f, 0.f, 0.f};

  const int klo = (q0 > WIN) ? (q0 - WIN) : 0;
  // windowed rows only; row 0's full-range attention is recomputed by
  // global_row_attn afterwards (overwrites AO row 0). khi <= q0+64+WIN always.
  int khi = q0 + 64 + WIN;
  if (khi > T_SEQ) khi = T_SEQ;

  const int sr = tid >> 3;
  const int sc = (tid & 7) * 8;

  // ---- software pipeline: regs hold next tile's K/V (T14 async-STAGE) ----
  int ti = (klo > 0) ? -1 : 0;          // ti==-1: global-token tile (kt=0)
  int kt = (klo > 0) ? 0 : klo;
  u16x8 kpre = *(const u16x8*)(K + hb + (size_t)(kt + sr) * DIM + sc);
  u16x8 vpre = *(const u16x8*)(V + hb + (size_t)(kt + sr) * DIM + sc);

  for (;;) {
    // write staged regs to LDS
    *(u16x8*)(Ks + sr * 72 + sc) = kpre;
    vt_dispatch(Vt, vpre, tid & 7, sc, sr);
    __syncthreads();

    // prefetch next tile into regs (global latency hides under compute)
    const int kt_n = klo + (ti + 1) * 32;
    const bool more = kt_n < khi;
    if (more) {
      kpre = *(const u16x8*)(K + hb + (size_t)(kt_n + sr) * DIM + sc);
      vpre = *(const u16x8*)(V + hb + (size_t)(kt_n + sr) * DIM + sc);
    }

    // ---- S = Q K^T ----
    f32x4 s0 = {0.f, 0.f, 0.f, 0.f}, s1 = {0.f, 0.f, 0.f, 0.f};
    {
      bf16x8 k00 = *(const bf16x8*)(Ks + c15 * 72 + g * 8);
      bf16x8 k01 = *(const bf16x8*)(Ks + c15 * 72 + 32 + g * 8);
      bf16x8 k10 = *(const bf16x8*)(Ks + (16 + c15) * 72 + g * 8);
      bf16x8 k11 = *(const bf16x8*)(Ks + (16 + c15) * 72 + 32 + g * 8);
      s0 = __builtin_amdgcn_mfma_f32_16x16x32_bf16(qf0, k00, s0, 0, 0, 0);
      s0 = __builtin_amdgcn_mfma_f32_16x16x32_bf16(qf1, k01, s0, 0, 0, 0);
      s1 = __builtin_amdgcn_mfma_f32_16x16x32_bf16(qf0, k10, s1, 0, 0, 0);
      s1 = __builtin_amdgcn_mfma_f32_16x16x32_bf16(qf1, k11, s1, 0, 0, 0);
    }
    // ---- mask + online softmax ----
#pragma unroll
    for (int j = 0; j < 4; ++j) {
      const int qg = q0 + wid * 16 + g * 4 + j;
      const int kg0 = kt + c15;
      const int kg1 = kg0 + 16;
      float v0 = s0[j] * 0.125f;
      float v1 = s1[j] * 0.125f;
      const int d0 = qg - kg0, d1 = qg - kg1;
      if (!((kg0 == 0) || (d0 <= WIN && d0 >= -WIN))) v0 = -1e30f;
      if (!((d1 <= WIN && d1 >= -WIN))) v1 = -1e30f;
      float rmax = fmaxf(v0, v1);
      rmax = fmaxf(rmax, __shfl_xor(rmax, 1));
      rmax = fmaxf(rmax, __shfl_xor(rmax, 2));
      rmax = fmaxf(rmax, __shfl_xor(rmax, 4));
      rmax = fmaxf(rmax, __shfl_xor(rmax, 8));
      const float mnew = fmaxf(mrun[j], rmax);
      const float p0 = __expf(v0 - mnew);
      const float p1 = __expf(v1 - mnew);
      float rs = p0 + p1;
      rs += __shfl_xor(rs, 1);
      rs += __shfl_xor(rs, 2);
      rs += __shfl_xor(rs, 4);
      rs += __shfl_xor(rs, 8);
      const float cr = __expf(mrun[j] - mnew);
      lrun[j] = lrun[j] * cr + rs;
      mrun[j] = mnew;
      corr[j] = cr;
      const int prow = g * 4 + j;
      Pl[wid][prow * 40 + c15] = f2bf(p0);
      Pl[wid][prow * 40 + 16 + c15] = f2bf(p1);
    }
#pragma unroll
    for (int c = 0; c < 4; ++c)
#pragma unroll
      for (int j = 0; j < 4; ++j) ao[c][j] *= corr[j];

    asm volatile("s_waitcnt lgkmcnt(0)" ::: "memory");

    // ---- O += P @ V ----
    const bf16x8 pa = *(const bf16x8*)(&Pl[wid][c15 * 40 + g * 8]);
#pragma unroll
    for (int c = 0; c < 4; ++c) {
      bf16x8 vf = *(const bf16x8*)(Vt + (c * 16 + c15) * 40 + g * 8);
      ao[c] = __builtin_amdgcn_mfma_f32_16x16x32_bf16(pa, vf, ao[c], 0, 0, 0);
    }
    __syncthreads();
    if (!more) break;
    ti++; kt = kt_n;
  }
#pragma unroll
  for (int j = 0; j < 4; ++j) {
    const int qrow = q0 + wid * 16 + g * 4 + j;
    const float inv = 1.0f / lrun[j];
#pragma unroll
    for (int c = 0; c < 4; ++c)
      AO[hb + (size_t)qrow * DIM + c * 16 + c15] = f2bf(ao[c][j] * inv);
  }
}

// ---------------- global row (row 0 attends everything) ----------------------
// One block per (b,h). Recomputes row 0 over all T keys, overwrites AO row 0.
__global__ __launch_bounds__(256) void global_row_attn(
    const u16* __restrict__ Q, const u16* __restrict__ K,
    const u16* __restrict__ V, u16* __restrict__ AO) {
  __shared__ float qs[HDIM];
  __shared__ float ps[T_SEQ];
  __shared__ float redm[4], reds[4];
  __shared__ float outp[4][HDIM];

  const int tid = threadIdx.x;
  const int lane = tid & 63;
  const int wv = tid >> 6;
  const size_t hb = (size_t)(blockIdx.x >> 4) * T_SEQ * DIM +
                    (size_t)(blockIdx.x & 15) * HDIM;

  if (tid < HDIM) qs[tid] = bf2f(Q[hb + tid]);
  __syncthreads();

  // logits for keys tid + 256*j
  float lg[8];
  float lmax = -1e30f;
#pragma unroll
  for (int j = 0; j < 8; ++j) {
    const u16* kr = K + hb + (size_t)(tid + 256 * j) * DIM;
    float acc = 0.f;
#pragma unroll
    for (int d0 = 0; d0 < 8; ++d0) {
      u16x8 kv = *(const u16x8*)(kr + d0 * 8);
#pragma unroll
      for (int e = 0; e < 8; ++e) acc += qs[d0 * 8 + e] * bf2f(kv[e]);
    }
    lg[j] = acc * 0.125f;
    lmax = fmaxf(lmax, lg[j]);
  }
#pragma unroll
  for (int s = 1; s < 64; s <<= 1) lmax = fmaxf(lmax, __shfl_xor(lmax, s));
  if (lane == 0) redm[wv] = lmax;
  __syncthreads();
  const float bmax = fmaxf(fmaxf(redm[0], redm[1]), fmaxf(redm[2], redm[3]));

  float lsum = 0.f;
#pragma unroll
  for (int j = 0; j < 8; ++j) {
    const float p = __expf(lg[j] - bmax);
    ps[tid + 256 * j] = p;
    lsum += p;
  }
#pragma unroll
  for (int s = 1; s < 64; s <<= 1) lsum += __shfl_xor(lsum, s);
  if (lane == 0) reds[wv] = lsum;
  __syncthreads();
  const float denom = reds[0] + reds[1] + reds[2] + reds[3];

  // out[d] = sum_k ps[k] * V[k][d]; wave wv owns key chunk wv*512..+512
  const int d = tid & 63;
  float acc = 0.f;
#pragma unroll 8
  for (int k = wv * 512; k < wv * 512 + 512; ++k)
    acc += ps[k] * bf2f(V[hb + (size_t)k * DIM + d]);
  outp[wv][d] = acc;
  __syncthreads();
  if (tid < HDIM) {
    const float tot = outp[0][tid] + outp[1][tid] + outp[2][tid] + outp[3][tid];
    AO[hb + tid] = f2bf(tot / denom);
  }
}

// ---------------- launch -----------------------------------------------------
extern "C" void kernel_launch(void* const* d_in, const int* in_sizes, int n_in,
                              void* d_out, int out_size, void* d_ws, size_t ws_size,
                              hipStream_t stream) {
  const float* x  = (const float*)d_in[0];
  const float* Wq = (const float*)d_in[1];
  const float* Wk = (const float*)d_in[2];
  const float* Wv = (const float*)d_in[3];
  const float* Wo = (const float*)d_in[4];
  float* out = (float*)d_out;

  const int XN = 2 * T_SEQ * DIM;
  const int WN = DIM * DIM;

  u16* ws  = (u16*)d_ws;
  u16* xb  = ws;                 // bf16 x; reused as AO after QKV
  u16* Wqb = ws + (size_t)XN;
  u16* Wkb = Wqb + WN;
  u16* Wvb = Wkb + WN;
  u16* Wob = Wvb + WN;
  u16* Qb  = Wob + WN;
  u16* Kb  = Qb + (size_t)XN;
  u16* Vb  = Kb + (size_t)XN;

  cvt_bf16<<<XN / 8 / 256, 256, 0, stream>>>(x, xb, XN / 8);
  cvt_bf16<<<WN / 8 / 256, 256, 0, stream>>>(Wq, Wqb, WN / 8);
  cvt_bf16<<<WN / 8 / 256, 256, 0, stream>>>(Wk, Wkb, WN / 8);
  cvt_bf16<<<WN / 8 / 256, 256, 0, stream>>>(Wv, Wvb, WN / 8);
  cvt_bf16<<<WN / 8 / 256, 256, 0, stream>>>(Wo, Wob, WN / 8);

  gemm_bt<u16><<<dim3(32, 24), 256, 0, stream>>>(xb, Wqb, Wkb, Wvb, Qb, Kb, Vb);

  sparse_attn<<<dim3(T_SEQ / 64, 16, 2), 256, 0, stream>>>(Qb, Kb, Vb, xb);
  global_row_attn<<<32, 256, 0, stream>>>(Qb, Kb, Vb, xb);

  gemm_bt<float><<<dim3(32, 8), 256, 0, stream>>>(xb, Wob, Wob, Wob, out, out, out);
}

// Round 3
// 171.026 us; speedup vs baseline: 2.1994x; 1.0413x over previous
//
#include <hip/hip_runtime.h>

typedef unsigned short u16;
typedef __attribute__((ext_vector_type(8))) __bf16 bf16x8;
typedef __attribute__((ext_vector_type(4))) float f32x4;
typedef __attribute__((ext_vector_type(8))) u16 u16x8;

#define T_SEQ 2048
#define DIM   1024
#define HDIM  64
#define WIN   128

__device__ __forceinline__ u16 f2bf(float f) {
  union { float f; unsigned u; } v; v.f = f;
  unsigned r = v.u + 0x7fffu + ((v.u >> 16) & 1u);  // RNE
  return (u16)(r >> 16);
}
__device__ __forceinline__ float bf2f(u16 u) {
  union { unsigned u; float f; } v; v.u = ((unsigned)u) << 16; return v.f;
}

// ---------------- fp32 -> bf16 convert (vectorized, 8/thread) ----------------
__global__ __launch_bounds__(256) void cvt_bf16(const float* __restrict__ s,
                                                u16* __restrict__ d, int n8) {
  int i = blockIdx.x * 256 + threadIdx.x;
  if (i >= n8) return;
  const float4* s4 = (const float4*)s;
  float4 a = s4[i * 2], b = s4[i * 2 + 1];
  u16x8 r;
  r[0] = f2bf(a.x); r[1] = f2bf(a.y); r[2] = f2bf(a.z); r[3] = f2bf(a.w);
  r[4] = f2bf(b.x); r[5] = f2bf(b.y); r[6] = f2bf(b.z); r[7] = f2bf(b.w);
  *(u16x8*)(d + i * 8) = r;
}

// ---------------- C = A @ B^T GEMM, phase-split + counted vmcnt --------------
// Double-buffered LDS; stage for K-tile t+1 issued at top of t; counted
// s_waitcnt vmcnt(SPW) (loads stay in flight across barriers); raw s_barrier
// (no compiler vmcnt(0) drain); NPH MFMA phases of 16 wrapped in setprio.
template <int BM, int BN, int WM, int WN, int NPH, typename OUT_T>
__global__ __launch_bounds__(WM * WN * 64) void gemm2(
    const u16* __restrict__ A, const u16* __restrict__ B0,
    const u16* __restrict__ B1, const u16* __restrict__ B2,
    OUT_T* __restrict__ C0, OUT_T* __restrict__ C1, OUT_T* __restrict__ C2) {
  constexpr int NW = WM * WN;
  constexpr int RM = BM / WM;   // per-wave output rows
  constexpr int RN = BN / WN;   // per-wave output cols
  constexpr int MF = RM / 16;
  constexpr int NF = RN / 16;
  constexpr int MPH = MF / NPH;
  constexpr int CA = BM / 8;    // A 1KB chunks (8 rows x 64 cols)
  constexpr int CB = BN / 8;
  constexpr int SPW = CA / NW + CB / NW;  // stage instrs per wave per K-tile
  constexpr int NB = DIM / BN;

  __shared__ u16 As[2][BM * 64];
  __shared__ u16 Bs[2][BN * 64];

  const int tid = threadIdx.x;
  const int lane = tid & 63;
  const int wid = tid >> 6;
  const int wr = wid / WN, wc = wid % WN;
  const int c15 = lane & 15, g = lane >> 4;
  const int bm = blockIdx.x;
  const int mat = blockIdx.y / NB, nb = blockIdx.y % NB;
  const u16* Bmat = (mat == 0) ? B0 : ((mat == 1) ? B1 : B2);
  OUT_T* Cmat = (mat == 0) ? C0 : ((mat == 1) ? C1 : C2);
  const u16* Ab = A + (size_t)bm * BM * DIM;
  const u16* Bb = Bmat + (size_t)nb * BN * DIM;

  const int lr = lane >> 3;        // row within 8-row chunk
  const int lc = (lane & 7) * 8;   // col group

  f32x4 acc[MF][NF];
#pragma unroll
  for (int m = 0; m < MF; ++m)
#pragma unroll
    for (int n = 0; n < NF; ++n) acc[m][n] = (f32x4){0.f, 0.f, 0.f, 0.f};

  auto stage = [&](int buf, int k0) {
#pragma unroll
    for (int i = 0; i < CA / NW; ++i) {
      const int c = wid + i * NW;
      __builtin_amdgcn_global_load_lds(
          (const __attribute__((address_space(1))) void*)(Ab + (size_t)(c * 8 + lr) * DIM + k0 + lc),
          (__attribute__((address_space(3))) void*)(&As[buf][c * 512]), 16, 0, 0);
    }
#pragma unroll
    for (int i = 0; i < CB / NW; ++i) {
      const int c = wid + i * NW;
      __builtin_amdgcn_global_load_lds(
          (const __attribute__((address_space(1))) void*)(Bb + (size_t)(c * 8 + lr) * DIM + k0 + lc),
          (__attribute__((address_space(3))) void*)(&Bs[buf][c * 512]), 16, 0, 0);
    }
  };

  stage(0, 0);
  int cur = 0;
  for (int k0 = 0; k0 < DIM; k0 += 64) {
    const bool more = (k0 + 64) < DIM;
    if (more) {
      stage(cur ^ 1, k0 + 64);
      if constexpr (SPW == 8) asm volatile("s_waitcnt vmcnt(8)" ::: "memory");
      else if constexpr (SPW == 6) asm volatile("s_waitcnt vmcnt(6)" ::: "memory");
      else asm volatile("s_waitcnt vmcnt(0)" ::: "memory");
    } else {
      asm volatile("s_waitcnt vmcnt(0)" ::: "memory");
    }
    __builtin_amdgcn_s_barrier();

    bf16x8 bfrag[NF][2];
#pragma unroll
    for (int ph = 0; ph < NPH; ++ph) {
      if (ph == 0) {
#pragma unroll
        for (int n = 0; n < NF; ++n)
#pragma unroll
          for (int ks = 0; ks < 2; ++ks)
            bfrag[n][ks] = *(const bf16x8*)(&Bs[cur][(wc * RN + n * 16 + c15) * 64 + ks * 32 + g * 8]);
      }
      bf16x8 afrag[MPH][2];
#pragma unroll
      for (int m = 0; m < MPH; ++m)
#pragma unroll
        for (int ks = 0; ks < 2; ++ks)
          afrag[m][ks] = *(const bf16x8*)(&As[cur][(wr * RM + (ph * MPH + m) * 16 + c15) * 64 + ks * 32 + g * 8]);
      __builtin_amdgcn_s_setprio(1);
#pragma unroll
      for (int m = 0; m < MPH; ++m)
#pragma unroll
        for (int n = 0; n < NF; ++n)
#pragma unroll
          for (int ks = 0; ks < 2; ++ks)
            acc[ph * MPH + m][n] = __builtin_amdgcn_mfma_f32_16x16x32_bf16(
                afrag[m][ks], bfrag[n][ks], acc[ph * MPH + m][n], 0, 0, 0);
      __builtin_amdgcn_s_setprio(0);
      __builtin_amdgcn_s_barrier();
    }
    cur ^= 1;
  }

  // epilogue: C/D layout col=lane&15, row=(lane>>4)*4+j
#pragma unroll
  for (int m = 0; m < MF; ++m) {
    const int row0 = bm * BM + wr * RM + m * 16 + g * 4;
#pragma unroll
    for (int n = 0; n < NF; ++n) {
      const int col = nb * BN + wc * RN + n * 16 + c15;
#pragma unroll
      for (int j = 0; j < 4; ++j) {
        const size_t idx = (size_t)(row0 + j) * DIM + col;
        if constexpr (sizeof(OUT_T) == 2) Cmat[idx] = f2bf(acc[m][n][j]);
        else Cmat[idx] = acc[m][n][j];
      }
    }
  }
}

// ---------------- sparse flash attention (windowed rows only) ----------------
template <int S>
__device__ __forceinline__ void vt_scatter(u16* __restrict__ Vt, const u16x8& vv,
                                           int sc, int sr) {
#pragma unroll
  for (int i = 0; i < 8; ++i) {
    const int e = (i + S) & 7;
    Vt[(sc + e) * 40 + sr] = vv[e];
  }
}
__device__ __forceinline__ void vt_dispatch(u16* __restrict__ Vt, const u16x8& vv,
                                            int sel, int sc, int sr) {
  switch (sel) {
    case 0: vt_scatter<0>(Vt, vv, sc, sr); break;
    case 1: vt_scatter<1>(Vt, vv, sc, sr); break;
    case 2: vt_scatter<2>(Vt, vv, sc, sr); break;
    case 3: vt_scatter<3>(Vt, vv, sc, sr); break;
    case 4: vt_scatter<4>(Vt, vv, sc, sr); break;
    case 5: vt_scatter<5>(Vt, vv, sc, sr); break;
    case 6: vt_scatter<6>(Vt, vv, sc, sr); break;
    case 7: vt_scatter<7>(Vt, vv, sc, sr); break;
  }
}

__global__ __launch_bounds__(256) void sparse_attn(
    const u16* __restrict__ Q, const u16* __restrict__ K,
    const u16* __restrict__ V, u16* __restrict__ AO) {
  __shared__ u16 Ks[32 * 72];
  __shared__ u16 Vt[64 * 40];
  __shared__ u16 Pl[4][16 * 40];

  const int tid = threadIdx.x;
  const int lane = tid & 63;
  const int wid = tid >> 6;
  const int c15 = lane & 15;
  const int g = lane >> 4;
  const int q0 = blockIdx.x * 64;
  const size_t hb = (size_t)blockIdx.z * T_SEQ * DIM + (size_t)blockIdx.y * HDIM;

  bf16x8 qf0, qf1;
  {
    const u16* qp = Q + hb + (size_t)(q0 + wid * 16 + c15) * DIM + g * 8;
    qf0 = *(const bf16x8*)qp;
    qf1 = *(const bf16x8*)(qp + 32);
  }

  float mrun[4], lrun[4], corr[4];
  f32x4 ao[4];
#pragma unroll
  for (int j = 0; j < 4; ++j) { mrun[j] = -1e30f; lrun[j] = 0.f; }
#pragma unroll
  for (int c = 0; c < 4; ++c) ao[c] = (f32x4){0.f, 0.f, 0.f, 0.f};

  const int klo = (q0 > WIN) ? (q0 - WIN) : 0;
  int khi = q0 + 64 + WIN;
  if (khi > T_SEQ) khi = T_SEQ;

  const int sr = tid >> 3;
  const int sc = (tid & 7) * 8;

  int ti = (klo > 0) ? -1 : 0;
  int kt = (klo > 0) ? 0 : klo;
  u16x8 kpre = *(const u16x8*)(K + hb + (size_t)(kt + sr) * DIM + sc);
  u16x8 vpre = *(const u16x8*)(V + hb + (size_t)(kt + sr) * DIM + sc);

  for (;;) {
    *(u16x8*)(Ks + sr * 72 + sc) = kpre;
    vt_dispatch(Vt, vpre, tid & 7, sc, sr);
    __syncthreads();

    const int kt_n = klo + (ti + 1) * 32;
    const bool more = kt_n < khi;
    if (more) {
      kpre = *(const u16x8*)(K + hb + (size_t)(kt_n + sr) * DIM + sc);
      vpre = *(const u16x8*)(V + hb + (size_t)(kt_n + sr) * DIM + sc);
    }

    f32x4 s0 = {0.f, 0.f, 0.f, 0.f}, s1 = {0.f, 0.f, 0.f, 0.f};
    {
      bf16x8 k00 = *(const bf16x8*)(Ks + c15 * 72 + g * 8);
      bf16x8 k01 = *(const bf16x8*)(Ks + c15 * 72 + 32 + g * 8);
      bf16x8 k10 = *(const bf16x8*)(Ks + (16 + c15) * 72 + g * 8);
      bf16x8 k11 = *(const bf16x8*)(Ks + (16 + c15) * 72 + 32 + g * 8);
      s0 = __builtin_amdgcn_mfma_f32_16x16x32_bf16(qf0, k00, s0, 0, 0, 0);
      s0 = __builtin_amdgcn_mfma_f32_16x16x32_bf16(qf1, k01, s0, 0, 0, 0);
      s1 = __builtin_amdgcn_mfma_f32_16x16x32_bf16(qf0, k10, s1, 0, 0, 0);
      s1 = __builtin_amdgcn_mfma_f32_16x16x32_bf16(qf1, k11, s1, 0, 0, 0);
    }
#pragma unroll
    for (int j = 0; j < 4; ++j) {
      const int qg = q0 + wid * 16 + g * 4 + j;
      const int kg0 = kt + c15;
      const int kg1 = kg0 + 16;
      float v0 = s0[j] * 0.125f;
      float v1 = s1[j] * 0.125f;
      const int d0 = qg - kg0, d1 = qg - kg1;
      if (!((kg0 == 0) || (d0 <= WIN && d0 >= -WIN))) v0 = -1e30f;
      if (!((d1 <= WIN && d1 >= -WIN))) v1 = -1e30f;
      float rmax = fmaxf(v0, v1);
      rmax = fmaxf(rmax, __shfl_xor(rmax, 1));
      rmax = fmaxf(rmax, __shfl_xor(rmax, 2));
      rmax = fmaxf(rmax, __shfl_xor(rmax, 4));
      rmax = fmaxf(rmax, __shfl_xor(rmax, 8));
      const float mnew = fmaxf(mrun[j], rmax);
      const float p0 = __expf(v0 - mnew);
      const float p1 = __expf(v1 - mnew);
      float rs = p0 + p1;
      rs += __shfl_xor(rs, 1);
      rs += __shfl_xor(rs, 2);
      rs += __shfl_xor(rs, 4);
      rs += __shfl_xor(rs, 8);
      const float cr = __expf(mrun[j] - mnew);
      lrun[j] = lrun[j] * cr + rs;
      mrun[j] = mnew;
      corr[j] = cr;
      const int prow = g * 4 + j;
      Pl[wid][prow * 40 + c15] = f2bf(p0);
      Pl[wid][prow * 40 + 16 + c15] = f2bf(p1);
    }
#pragma unroll
    for (int c = 0; c < 4; ++c)
#pragma unroll
      for (int j = 0; j < 4; ++j) ao[c][j] *= corr[j];

    asm volatile("s_waitcnt lgkmcnt(0)" ::: "memory");

    const bf16x8 pa = *(const bf16x8*)(&Pl[wid][c15 * 40 + g * 8]);
#pragma unroll
    for (int c = 0; c < 4; ++c) {
      bf16x8 vf = *(const bf16x8*)(Vt + (c * 16 + c15) * 40 + g * 8);
      ao[c] = __builtin_amdgcn_mfma_f32_16x16x32_bf16(pa, vf, ao[c], 0, 0, 0);
    }
    __syncthreads();
    if (!more) break;
    ti++; kt = kt_n;
  }
#pragma unroll
  for (int j = 0; j < 4; ++j) {
    const int qrow = q0 + wid * 16 + g * 4 + j;
    const float inv = 1.0f / lrun[j];
#pragma unroll
    for (int c = 0; c < 4; ++c)
      AO[hb + (size_t)qrow * DIM + c * 16 + c15] = f2bf(ao[c][j] * inv);
  }
}

// ---------------- global row (row 0 attends everything) ----------------------
__global__ __launch_bounds__(256) void global_row_attn(
    const u16* __restrict__ Q, const u16* __restrict__ K,
    const u16* __restrict__ V, u16* __restrict__ AO) {
  __shared__ float qs[HDIM];
  __shared__ float ps[T_SEQ];
  __shared__ float redm[4], reds[4];
  __shared__ float outp[4][HDIM];

  const int tid = threadIdx.x;
  const int lane = tid & 63;
  const int wv = tid >> 6;
  const size_t hb = (size_t)(blockIdx.x >> 4) * T_SEQ * DIM +
                    (size_t)(blockIdx.x & 15) * HDIM;

  if (tid < HDIM) qs[tid] = bf2f(Q[hb + tid]);
  __syncthreads();

  float lg[8];
  float lmax = -1e30f;
#pragma unroll
  for (int j = 0; j < 8; ++j) {
    const u16* kr = K + hb + (size_t)(tid + 256 * j) * DIM;
    float acc = 0.f;
#pragma unroll
    for (int d0 = 0; d0 < 8; ++d0) {
      u16x8 kv = *(const u16x8*)(kr + d0 * 8);
#pragma unroll
      for (int e = 0; e < 8; ++e) acc += qs[d0 * 8 + e] * bf2f(kv[e]);
    }
    lg[j] = acc * 0.125f;
    lmax = fmaxf(lmax, lg[j]);
  }
#pragma unroll
  for (int s = 1; s < 64; s <<= 1) lmax = fmaxf(lmax, __shfl_xor(lmax, s));
  if (lane == 0) redm[wv] = lmax;
  __syncthreads();
  const float bmax = fmaxf(fmaxf(redm[0], redm[1]), fmaxf(redm[2], redm[3]));

  float lsum = 0.f;
#pragma unroll
  for (int j = 0; j < 8; ++j) {
    const float p = __expf(lg[j] - bmax);
    ps[tid + 256 * j] = p;
    lsum += p;
  }
#pragma unroll
  for (int s = 1; s < 64; s <<= 1) lsum += __shfl_xor(lsum, s);
  if (lane == 0) reds[wv] = lsum;
  __syncthreads();
  const float denom = reds[0] + reds[1] + reds[2] + reds[3];

  const int d = tid & 63;
  float acc = 0.f;
#pragma unroll 8
  for (int k = wv * 512; k < wv * 512 + 512; ++k)
    acc += ps[k] * bf2f(V[hb + (size_t)k * DIM + d]);
  outp[wv][d] = acc;
  __syncthreads();
  if (tid < HDIM) {
    const float tot = outp[0][tid] + outp[1][tid] + outp[2][tid] + outp[3][tid];
    AO[hb + tid] = f2bf(tot / denom);
  }
}

// ---------------- launch -----------------------------------------------------
extern "C" void kernel_launch(void* const* d_in, const int* in_sizes, int n_in,
                              void* d_out, int out_size, void* d_ws, size_t ws_size,
                              hipStream_t stream) {
  const float* x  = (const float*)d_in[0];
  const float* Wq = (const float*)d_in[1];
  const float* Wk = (const float*)d_in[2];
  const float* Wv = (const float*)d_in[3];
  const float* Wo = (const float*)d_in[4];
  float* out = (float*)d_out;

  const int XN = 2 * T_SEQ * DIM;
  const int WN = DIM * DIM;

  u16* ws  = (u16*)d_ws;
  u16* xb  = ws;                 // bf16 x; reused as AO after QKV
  u16* Wqb = ws + (size_t)XN;
  u16* Wkb = Wqb + WN;
  u16* Wvb = Wkb + WN;
  u16* Wob = Wvb + WN;
  u16* Qb  = Wob + WN;
  u16* Kb  = Qb + (size_t)XN;
  u16* Vb  = Kb + (size_t)XN;

  cvt_bf16<<<XN / 8 / 256, 256, 0, stream>>>(x, xb, XN / 8);
  cvt_bf16<<<WN / 8 / 256, 256, 0, stream>>>(Wq, Wqb, WN / 8);
  cvt_bf16<<<WN / 8 / 256, 256, 0, stream>>>(Wk, Wkb, WN / 8);
  cvt_bf16<<<WN / 8 / 256, 256, 0, stream>>>(Wv, Wvb, WN / 8);
  cvt_bf16<<<WN / 8 / 256, 256, 0, stream>>>(Wo, Wob, WN / 8);

  // fused QKV projection: 256x256 tiles, 8 waves, 4 MFMA phases, vmcnt(8)
  gemm2<256, 256, 2, 4, 4, u16><<<dim3(16, 12), 512, 0, stream>>>(
      xb, Wqb, Wkb, Wvb, Qb, Kb, Vb);

  sparse_attn<<<dim3(T_SEQ / 64, 16, 2), 256, 0, stream>>>(Qb, Kb, Vb, xb);
  global_row_attn<<<32, 256, 0, stream>>>(Qb, Kb, Vb, xb);

  // output projection: 64x128 tiles, 4 waves, single phase, vmcnt(6)
  gemm2<64, 128, 2, 2, 1, float><<<dim3(64, 8), 256, 0, stream>>>(
      xb, Wob, Wob, Wob, out, out, out);
}

// Round 4
// 167.828 us; speedup vs baseline: 2.2413x; 1.0191x over previous
//
#include <hip/hip_runtime.h>

typedef unsigned short u16;
typedef __attribute__((ext_vector_type(8))) __bf16 bf16x8;
typedef __attribute__((ext_vector_type(4))) float f32x4;
typedef __attribute__((ext_vector_type(8))) u16 u16x8;

#define T_SEQ 2048
#define DIM   1024
#define HDIM  64
#define WIN   128

#define AS1 __attribute__((address_space(1)))
#define AS3 __attribute__((address_space(3)))

__device__ __forceinline__ u16 f2bf(float f) {
  union { float f; unsigned u; } v; v.f = f;
  unsigned r = v.u + 0x7fffu + ((v.u >> 16) & 1u);  // RNE
  return (u16)(r >> 16);
}
__device__ __forceinline__ float bf2f(u16 u) {
  union { unsigned u; float f; } v; v.u = ((unsigned)u) << 16; return v.f;
}
__device__ __forceinline__ void bar() {
  asm volatile("" ::: "memory");
  __builtin_amdgcn_s_barrier();
  asm volatile("" ::: "memory");
}

// ---------------- fp32 -> bf16 converts --------------------------------------
__global__ __launch_bounds__(256) void cvt_bf16(const float* __restrict__ s,
                                                u16* __restrict__ d, int n8) {
  int i = blockIdx.x * 256 + threadIdx.x;
  if (i >= n8) return;
  const float4* s4 = (const float4*)s;
  float4 a = s4[i * 2], b = s4[i * 2 + 1];
  u16x8 r;
  r[0] = f2bf(a.x); r[1] = f2bf(a.y); r[2] = f2bf(a.z); r[3] = f2bf(a.w);
  r[4] = f2bf(b.x); r[5] = f2bf(b.y); r[6] = f2bf(b.z); r[7] = f2bf(b.w);
  *(u16x8*)(d + i * 8) = r;
}
__global__ __launch_bounds__(256) void cvt_w4(
    const float* __restrict__ s0, const float* __restrict__ s1,
    const float* __restrict__ s2, const float* __restrict__ s3,
    u16* __restrict__ d0, u16* __restrict__ d1,
    u16* __restrict__ d2, u16* __restrict__ d3) {
  const int y = blockIdx.y;
  const float* s = (y == 0) ? s0 : ((y == 1) ? s1 : ((y == 2) ? s2 : s3));
  u16* d = (y == 0) ? d0 : ((y == 1) ? d1 : ((y == 2) ? d2 : d3));
  int i = blockIdx.x * 256 + threadIdx.x;
  const float4* s4 = (const float4*)s;
  float4 a = s4[i * 2], b = s4[i * 2 + 1];
  u16x8 r;
  r[0] = f2bf(a.x); r[1] = f2bf(a.y); r[2] = f2bf(a.z); r[3] = f2bf(a.w);
  r[4] = f2bf(b.x); r[5] = f2bf(b.y); r[6] = f2bf(b.z); r[7] = f2bf(b.w);
  *(u16x8*)(d + i * 8) = r;
}

// ---------------- C = A @ B^T, 4-phase pipelined + T2 swizzle ---------------
// Per K-tile: 4 phases (one M-quadrant x K=64 each). Each phase:
//   {ds_read frags; stage 1 half-tile; [P3: counted vmcnt]; bar; setprio(1);
//    MFMA cluster; setprio(0); bar}
// Stage ring (all targets barrier-separated from their last reader):
//   P0: A-half0(t+1)  P1: A-half1(t+1)  P2: B-half0(t+2)  P3: B-half1(t+2)
// vmcnt(4) at P3 publishes tile t+1 (A staged this iter, B staged last iter);
// tail: vmcnt(0) once trailing B stages are skipped. Never drains mid-loop.
// T2: linear LDS dest (global_load_lds), inverse-swizzled global source col,
// XOR ((row&7)<<3) on ds_read address (rule #21 both-sides).
template <int BM, int BN, int WM, int WN, typename OUT_T>
__global__ __launch_bounds__(WM * WN * 64, 2) void gemm3(
    const u16* __restrict__ A, const u16* __restrict__ Bm0,
    const u16* __restrict__ Bm1, const u16* __restrict__ Bm2,
    OUT_T* __restrict__ Cm0, OUT_T* __restrict__ Cm1, OUT_T* __restrict__ Cm2,
    int nbm) {
  constexpr int NW = WM * WN;
  constexpr int RM = BM / WM, RN = BN / WN;
  constexpr int MF = RM / 16, NF = RN / 16;
  constexpr int MPH = MF / 4;                 // m-frags per phase
  constexpr int NT = DIM / 64;                // K-tiles
  constexpr int NB = DIM / BN;                // n-blocks per matrix

  __shared__ u16 As[2][BM * 64];
  __shared__ u16 Bs[2][BN * 64];

  const int tid = threadIdx.x;
  const int lane = tid & 63;
  const int wid = tid >> 6;
  const int wr = wid / WN, wc = wid % WN;
  const int c15 = lane & 15, g = lane >> 4;
  const int lr = lane >> 3;                   // 0..7
  const int lcs = ((lane & 7) ^ lr) << 3;     // inverse-swizzled col (u16)

  // bijective XCD swizzle (grid % 8 == 0)
  const int cpx = gridDim.x >> 3;
  const int bid = ((int)blockIdx.x & 7) * cpx + ((int)blockIdx.x >> 3);
  const int bm = bid % nbm;
  const int by = bid / nbm;
  const int mat = by / NB, nb = by % NB;
  const u16* Bmat = (mat == 0) ? Bm0 : ((mat == 1) ? Bm1 : Bm2);
  OUT_T* Cmat = (mat == 0) ? Cm0 : ((mat == 1) ? Cm1 : Cm2);
  const u16* Ab = A + (size_t)bm * BM * DIM;
  const u16* Bb = Bmat + (size_t)nb * BN * DIM;

  f32x4 acc[MF][NF];
#pragma unroll
  for (int m = 0; m < MF; ++m)
#pragma unroll
    for (int n = 0; n < NF; ++n) acc[m][n] = (f32x4){0.f, 0.f, 0.f, 0.f};

  auto stA = [&](int buf, int half, int k0) {
#pragma unroll
    for (int i = 0; i < 2; ++i) {
      const int c = half * (BM / 16) + wid * 2 + i;
      __builtin_amdgcn_global_load_lds(
          (const AS1 void*)(Ab + (size_t)(c * 8 + lr) * DIM + k0 + lcs),
          (AS3 void*)(&As[buf][c * 512]), 16, 0, 0);
    }
  };
  auto stB = [&](int buf, int half, int k0) {
#pragma unroll
    for (int i = 0; i < 2; ++i) {
      const int c = half * (BN / 16) + wid * 2 + i;
      __builtin_amdgcn_global_load_lds(
          (const AS1 void*)(Bb + (size_t)(c * 8 + lr) * DIM + k0 + lcs),
          (AS3 void*)(&Bs[buf][c * 512]), 16, 0, 0);
    }
  };

  // prologue: tile0 A+B, tile1 B. vmcnt(4) keeps B(1) in flight.
  stA(0, 0, 0); stA(0, 1, 0);
  stB(0, 0, 0); stB(0, 1, 0);
  stB(1, 0, 64); stB(1, 1, 64);
  asm volatile("s_waitcnt vmcnt(4)" ::: "memory");
  bar();

  for (int t = 0; t < NT; ++t) {
    const int buf = t & 1;
    const int k0 = t * 64;
    bf16x8 bfrag[NF][2];
#pragma unroll
    for (int p = 0; p < 4; ++p) {
      if (p == 0) {
#pragma unroll
        for (int n = 0; n < NF; ++n)
#pragma unroll
          for (int ks = 0; ks < 2; ++ks) {
            const int r = wc * RN + n * 16 + c15;
            bfrag[n][ks] = *(const bf16x8*)(
                &Bs[buf][r * 64 + ((ks * 32 + g * 8) ^ ((r & 7) << 3))]);
          }
      }
      bf16x8 af[MPH][2];
#pragma unroll
      for (int m = 0; m < MPH; ++m)
#pragma unroll
        for (int ks = 0; ks < 2; ++ks) {
          const int r = wr * RM + (p * MPH + m) * 16 + c15;
          af[m][ks] = *(const bf16x8*)(
              &As[buf][r * 64 + ((ks * 32 + g * 8) ^ ((r & 7) << 3))]);
        }
      if (p == 0) {
        if (t + 1 < NT) stA(buf ^ 1, 0, k0 + 64);
      } else if (p == 1) {
        if (t + 1 < NT) stA(buf ^ 1, 1, k0 + 64);
      } else if (p == 2) {
        if (t + 2 < NT) stB(buf, 0, k0 + 128);
      } else {
        if (t + 2 < NT) stB(buf, 1, k0 + 128);
        if (t < NT - 2) asm volatile("s_waitcnt vmcnt(4)" ::: "memory");
        else            asm volatile("s_waitcnt vmcnt(0)" ::: "memory");
      }
      bar();
      __builtin_amdgcn_s_setprio(1);
#pragma unroll
      for (int m = 0; m < MPH; ++m)
#pragma unroll
        for (int n = 0; n < NF; ++n)
#pragma unroll
          for (int ks = 0; ks < 2; ++ks)
            acc[p * MPH + m][n] = __builtin_amdgcn_mfma_f32_16x16x32_bf16(
                af[m][ks], bfrag[n][ks], acc[p * MPH + m][n], 0, 0, 0);
      __builtin_amdgcn_s_setprio(0);
      bar();
    }
  }

  // epilogue: C/D layout col=lane&15, row=(lane>>4)*4+j
#pragma unroll
  for (int m = 0; m < MF; ++m) {
    const int row0 = bm * BM + wr * RM + m * 16 + g * 4;
#pragma unroll
    for (int n = 0; n < NF; ++n) {
      const int col = nb * BN + wc * RN + n * 16 + c15;
#pragma unroll
      for (int j = 0; j < 4; ++j) {
        const size_t idx = (size_t)(row0 + j) * DIM + col;
        if constexpr (sizeof(OUT_T) == 2) Cmat[idx] = f2bf(acc[m][n][j]);
        else Cmat[idx] = acc[m][n][j];
      }
    }
  }
}

// ---------------- sparse flash attention (windowed rows only) ----------------
template <int S>
__device__ __forceinline__ void vt_scatter(u16* __restrict__ Vt, const u16x8& vv,
                                           int sc, int sr) {
#pragma unroll
  for (int i = 0; i < 8; ++i) {
    const int e = (i + S) & 7;
    Vt[(sc + e) * 40 + sr] = vv[e];
  }
}
__device__ __forceinline__ void vt_dispatch(u16* __restrict__ Vt, const u16x8& vv,
                                            int sel, int sc, int sr) {
  switch (sel) {
    case 0: vt_scatter<0>(Vt, vv, sc, sr); break;
    case 1: vt_scatter<1>(Vt, vv, sc, sr); break;
    case 2: vt_scatter<2>(Vt, vv, sc, sr); break;
    case 3: vt_scatter<3>(Vt, vv, sc, sr); break;
    case 4: vt_scatter<4>(Vt, vv, sc, sr); break;
    case 5: vt_scatter<5>(Vt, vv, sc, sr); break;
    case 6: vt_scatter<6>(Vt, vv, sc, sr); break;
    case 7: vt_scatter<7>(Vt, vv, sc, sr); break;
  }
}

__global__ __launch_bounds__(256) void sparse_attn(
    const u16* __restrict__ Q, const u16* __restrict__ K,
    const u16* __restrict__ V, u16* __restrict__ AO) {
  __shared__ u16 Ks[32 * 72];
  __shared__ u16 Vt[64 * 40];
  __shared__ u16 Pl[4][16 * 40];

  const int tid = threadIdx.x;
  const int lane = tid & 63;
  const int wid = tid >> 6;
  const int c15 = lane & 15;
  const int g = lane >> 4;
  const int q0 = blockIdx.x * 64;
  const size_t hb = (size_t)blockIdx.z * T_SEQ * DIM + (size_t)blockIdx.y * HDIM;

  bf16x8 qf0, qf1;
  {
    const u16* qp = Q + hb + (size_t)(q0 + wid * 16 + c15) * DIM + g * 8;
    qf0 = *(const bf16x8*)qp;
    qf1 = *(const bf16x8*)(qp + 32);
  }

  float mrun[4], lrun[4], corr[4];
  f32x4 ao[4];
#pragma unroll
  for (int j = 0; j < 4; ++j) { mrun[j] = -1e30f; lrun[j] = 0.f; }
#pragma unroll
  for (int c = 0; c < 4; ++c) ao[c] = (f32x4){0.f, 0.f, 0.f, 0.f};

  const int klo = (q0 > WIN) ? (q0 - WIN) : 0;
  int khi = q0 + 64 + WIN;
  if (khi > T_SEQ) khi = T_SEQ;

  const int sr = tid >> 3;
  const int sc = (tid & 7) * 8;

  int ti = (klo > 0) ? -1 : 0;
  int kt = (klo > 0) ? 0 : klo;
  u16x8 kpre = *(const u16x8*)(K + hb + (size_t)(kt + sr) * DIM + sc);
  u16x8 vpre = *(const u16x8*)(V + hb + (size_t)(kt + sr) * DIM + sc);

  for (;;) {
    *(u16x8*)(Ks + sr * 72 + sc) = kpre;
    vt_dispatch(Vt, vpre, tid & 7, sc, sr);
    __syncthreads();

    const int kt_n = klo + (ti + 1) * 32;
    const bool more = kt_n < khi;
    if (more) {
      kpre = *(const u16x8*)(K + hb + (size_t)(kt_n + sr) * DIM + sc);
      vpre = *(const u16x8*)(V + hb + (size_t)(kt_n + sr) * DIM + sc);
    }

    f32x4 s0 = {0.f, 0.f, 0.f, 0.f}, s1 = {0.f, 0.f, 0.f, 0.f};
    {
      bf16x8 k00 = *(const bf16x8*)(Ks + c15 * 72 + g * 8);
      bf16x8 k01 = *(const bf16x8*)(Ks + c15 * 72 + 32 + g * 8);
      bf16x8 k10 = *(const bf16x8*)(Ks + (16 + c15) * 72 + g * 8);
      bf16x8 k11 = *(const bf16x8*)(Ks + (16 + c15) * 72 + 32 + g * 8);
      s0 = __builtin_amdgcn_mfma_f32_16x16x32_bf16(qf0, k00, s0, 0, 0, 0);
      s0 = __builtin_amdgcn_mfma_f32_16x16x32_bf16(qf1, k01, s0, 0, 0, 0);
      s1 = __builtin_amdgcn_mfma_f32_16x16x32_bf16(qf0, k10, s1, 0, 0, 0);
      s1 = __builtin_amdgcn_mfma_f32_16x16x32_bf16(qf1, k11, s1, 0, 0, 0);
    }
#pragma unroll
    for (int j = 0; j < 4; ++j) {
      const int qg = q0 + wid * 16 + g * 4 + j;
      const int kg0 = kt + c15;
      const int kg1 = kg0 + 16;
      float v0 = s0[j] * 0.125f;
      float v1 = s1[j] * 0.125f;
      const int d0 = qg - kg0, d1 = qg - kg1;
      if (!((kg0 == 0) || (d0 <= WIN && d0 >= -WIN))) v0 = -1e30f;
      if (!((d1 <= WIN && d1 >= -WIN))) v1 = -1e30f;
      float rmax = fmaxf(v0, v1);
      rmax = fmaxf(rmax, __shfl_xor(rmax, 1));
      rmax = fmaxf(rmax, __shfl_xor(rmax, 2));
      rmax = fmaxf(rmax, __shfl_xor(rmax, 4));
      rmax = fmaxf(rmax, __shfl_xor(rmax, 8));
      const float mnew = fmaxf(mrun[j], rmax);
      const float p0 = __expf(v0 - mnew);
      const float p1 = __expf(v1 - mnew);
      float rs = p0 + p1;
      rs += __shfl_xor(rs, 1);
      rs += __shfl_xor(rs, 2);
      rs += __shfl_xor(rs, 4);
      rs += __shfl_xor(rs, 8);
      const float cr = __expf(mrun[j] - mnew);
      lrun[j] = lrun[j] * cr + rs;
      mrun[j] = mnew;
      corr[j] = cr;
      const int prow = g * 4 + j;
      Pl[wid][prow * 40 + c15] = f2bf(p0);
      Pl[wid][prow * 40 + 16 + c15] = f2bf(p1);
    }
#pragma unroll
    for (int c = 0; c < 4; ++c)
#pragma unroll
      for (int j = 0; j < 4; ++j) ao[c][j] *= corr[j];

    asm volatile("s_waitcnt lgkmcnt(0)" ::: "memory");

    const bf16x8 pa = *(const bf16x8*)(&Pl[wid][c15 * 40 + g * 8]);
#pragma unroll
    for (int c = 0; c < 4; ++c) {
      bf16x8 vf = *(const bf16x8*)(Vt + (c * 16 + c15) * 40 + g * 8);
      ao[c] = __builtin_amdgcn_mfma_f32_16x16x32_bf16(pa, vf, ao[c], 0, 0, 0);
    }
    __syncthreads();
    if (!more) break;
    ti++; kt = kt_n;
  }
#pragma unroll
  for (int j = 0; j < 4; ++j) {
    const int qrow = q0 + wid * 16 + g * 4 + j;
    const float inv = 1.0f / lrun[j];
#pragma unroll
    for (int c = 0; c < 4; ++c)
      AO[hb + (size_t)qrow * DIM + c * 16 + c15] = f2bf(ao[c][j] * inv);
  }
}

// ---------------- global row (row 0 attends everything) ----------------------
__global__ __launch_bounds__(256) void global_row_attn(
    const u16* __restrict__ Q, const u16* __restrict__ K,
    const u16* __restrict__ V, u16* __restrict__ AO) {
  __shared__ float qs[HDIM];
  __shared__ float ps[T_SEQ];
  __shared__ float redm[4], reds[4];
  __shared__ float outp[4][HDIM];

  const int tid = threadIdx.x;
  const int lane = tid & 63;
  const int wv = tid >> 6;
  const size_t hb = (size_t)(blockIdx.x >> 4) * T_SEQ * DIM +
                    (size_t)(blockIdx.x & 15) * HDIM;

  if (tid < HDIM) qs[tid] = bf2f(Q[hb + tid]);
  __syncthreads();

  float lg[8];
  float lmax = -1e30f;
#pragma unroll
  for (int j = 0; j < 8; ++j) {
    const u16* kr = K + hb + (size_t)(tid + 256 * j) * DIM;
    float acc = 0.f;
#pragma unroll
    for (int d0 = 0; d0 < 8; ++d0) {
      u16x8 kv = *(const u16x8*)(kr + d0 * 8);
#pragma unroll
      for (int e = 0; e < 8; ++e) acc += qs[d0 * 8 + e] * bf2f(kv[e]);
    }
    lg[j] = acc * 0.125f;
    lmax = fmaxf(lmax, lg[j]);
  }
#pragma unroll
  for (int s = 1; s < 64; s <<= 1) lmax = fmaxf(lmax, __shfl_xor(lmax, s));
  if (lane == 0) redm[wv] = lmax;
  __syncthreads();
  const float bmax = fmaxf(fmaxf(redm[0], redm[1]), fmaxf(redm[2], redm[3]));

  float lsum = 0.f;
#pragma unroll
  for (int j = 0; j < 8; ++j) {
    const float p = __expf(lg[j] - bmax);
    ps[tid + 256 * j] = p;
    lsum += p;
  }
#pragma unroll
  for (int s = 1; s < 64; s <<= 1) lsum += __shfl_xor(lsum, s);
  if (lane == 0) reds[wv] = lsum;
  __syncthreads();
  const float denom = reds[0] + reds[1] + reds[2] + reds[3];

  const int d = tid & 63;
  float acc = 0.f;
#pragma unroll 8
  for (int k = wv * 512; k < wv * 512 + 512; ++k)
    acc += ps[k] * bf2f(V[hb + (size_t)k * DIM + d]);
  outp[wv][d] = acc;
  __syncthreads();
  if (tid < HDIM) {
    const float tot = outp[0][tid] + outp[1][tid] + outp[2][tid] + outp[3][tid];
    AO[hb + tid] = f2bf(tot / denom);
  }
}

// ---------------- launch -----------------------------------------------------
extern "C" void kernel_launch(void* const* d_in, const int* in_sizes, int n_in,
                              void* d_out, int out_size, void* d_ws, size_t ws_size,
                              hipStream_t stream) {
  const float* x  = (const float*)d_in[0];
  const float* Wq = (const float*)d_in[1];
  const float* Wk = (const float*)d_in[2];
  const float* Wv = (const float*)d_in[3];
  const float* Wo = (const float*)d_in[4];
  float* out = (float*)d_out;

  const int XN = 2 * T_SEQ * DIM;
  const int WN = DIM * DIM;

  u16* ws  = (u16*)d_ws;
  u16* xb  = ws;                 // bf16 x; reused as AO after QKV
  u16* Wqb = ws + (size_t)XN;
  u16* Wkb = Wqb + WN;
  u16* Wvb = Wkb + WN;
  u16* Wob = Wvb + WN;
  u16* Qb  = Wob + WN;
  u16* Kb  = Qb + (size_t)XN;
  u16* Vb  = Kb + (size_t)XN;

  cvt_bf16<<<XN / 8 / 256, 256, 0, stream>>>(x, xb, XN / 8);
  cvt_w4<<<dim3(WN / 8 / 256, 4), 256, 0, stream>>>(Wq, Wk, Wv, Wo,
                                                    Wqb, Wkb, Wvb, Wob);

  // fused QKV projection: 256x256 tiles, 8 waves, 4-phase pipeline, grid 192
  gemm3<256, 256, 2, 4, u16><<<192, 512, 0, stream>>>(
      xb, Wqb, Wkb, Wvb, Qb, Kb, Vb, 16);

  sparse_attn<<<dim3(T_SEQ / 64, 16, 2), 256, 0, stream>>>(Qb, Kb, Vb, xb);
  global_row_attn<<<32, 256, 0, stream>>>(Qb, Kb, Vb, xb);

  // output projection: 128x128 tiles, 4 waves, grid 256 (full CU coverage)
  gemm3<128, 128, 2, 2, float><<<256, 256, 0, stream>>>(
      xb, Wob, Wob, Wob, out, out, out, 32);
}

// Round 5
// 140.090 us; speedup vs baseline: 2.6851x; 1.1980x over previous
//
#include <hip/hip_runtime.h>

typedef unsigned short u16;
typedef __attribute__((ext_vector_type(8))) __bf16 bf16x8;
typedef __attribute__((ext_vector_type(4))) float f32x4;
typedef __attribute__((ext_vector_type(8))) u16 u16x8;

#define T_SEQ 2048
#define DIM   1024
#define HDIM  64
#define WIN   128

#define AS1 __attribute__((address_space(1)))
#define AS3 __attribute__((address_space(3)))

__device__ __forceinline__ u16 f2bf(float f) {
  union { float f; unsigned u; } v; v.f = f;
  unsigned r = v.u + 0x7fffu + ((v.u >> 16) & 1u);  // RNE
  return (u16)(r >> 16);
}
__device__ __forceinline__ float bf2f(u16 u) {
  union { unsigned u; float f; } v; v.u = ((unsigned)u) << 16; return v.f;
}
__device__ __forceinline__ void bar() {
  asm volatile("" ::: "memory");
  __builtin_amdgcn_s_barrier();
  asm volatile("" ::: "memory");
}

// ---------------- fp32 -> bf16 converts --------------------------------------
__global__ __launch_bounds__(256) void cvt_bf16(const float* __restrict__ s,
                                                u16* __restrict__ d, int n8) {
  int i = blockIdx.x * 256 + threadIdx.x;
  if (i >= n8) return;
  const float4* s4 = (const float4*)s;
  float4 a = s4[i * 2], b = s4[i * 2 + 1];
  u16x8 r;
  r[0] = f2bf(a.x); r[1] = f2bf(a.y); r[2] = f2bf(a.z); r[3] = f2bf(a.w);
  r[4] = f2bf(b.x); r[5] = f2bf(b.y); r[6] = f2bf(b.z); r[7] = f2bf(b.w);
  *(u16x8*)(d + i * 8) = r;
}
__global__ __launch_bounds__(256) void cvt_w4(
    const float* __restrict__ s0, const float* __restrict__ s1,
    const float* __restrict__ s2, const float* __restrict__ s3,
    u16* __restrict__ d0, u16* __restrict__ d1,
    u16* __restrict__ d2, u16* __restrict__ d3) {
  const int y = blockIdx.y;
  const float* s = (y == 0) ? s0 : ((y == 1) ? s1 : ((y == 2) ? s2 : s3));
  u16* d = (y == 0) ? d0 : ((y == 1) ? d1 : ((y == 2) ? d2 : d3));
  int i = blockIdx.x * 256 + threadIdx.x;
  const float4* s4 = (const float4*)s;
  float4 a = s4[i * 2], b = s4[i * 2 + 1];
  u16x8 r;
  r[0] = f2bf(a.x); r[1] = f2bf(a.y); r[2] = f2bf(a.z); r[3] = f2bf(a.w);
  r[4] = f2bf(b.x); r[5] = f2bf(b.y); r[6] = f2bf(b.z); r[7] = f2bf(b.w);
  *(u16x8*)(d + i * 8) = r;
}

// ---------------- C = A @ B^T, 4-phase pipelined + T2 swizzle ---------------
template <int BM, int BN, int WM, int WN, typename OUT_T>
__global__ __launch_bounds__(WM * WN * 64, 2) void gemm3(
    const u16* __restrict__ A, const u16* __restrict__ Bm0,
    const u16* __restrict__ Bm1, const u16* __restrict__ Bm2,
    OUT_T* __restrict__ Cm0, OUT_T* __restrict__ Cm1, OUT_T* __restrict__ Cm2,
    int nbm) {
  constexpr int NW = WM * WN;
  constexpr int RM = BM / WM, RN = BN / WN;
  constexpr int MF = RM / 16, NF = RN / 16;
  constexpr int MPH = MF / 4;
  constexpr int NT = DIM / 64;
  constexpr int NB = DIM / BN;

  __shared__ u16 As[2][BM * 64];
  __shared__ u16 Bs[2][BN * 64];

  const int tid = threadIdx.x;
  const int lane = tid & 63;
  const int wid = tid >> 6;
  const int wr = wid / WN, wc = wid % WN;
  const int c15 = lane & 15, g = lane >> 4;
  const int lr = lane >> 3;
  const int lcs = ((lane & 7) ^ lr) << 3;

  const int cpx = gridDim.x >> 3;
  const int bid = ((int)blockIdx.x & 7) * cpx + ((int)blockIdx.x >> 3);
  const int bm = bid % nbm;
  const int by = bid / nbm;
  const int mat = by / NB, nb = by % NB;
  const u16* Bmat = (mat == 0) ? Bm0 : ((mat == 1) ? Bm1 : Bm2);
  OUT_T* Cmat = (mat == 0) ? Cm0 : ((mat == 1) ? Cm1 : Cm2);
  const u16* Ab = A + (size_t)bm * BM * DIM;
  const u16* Bb = Bmat + (size_t)nb * BN * DIM;

  f32x4 acc[MF][NF];
#pragma unroll
  for (int m = 0; m < MF; ++m)
#pragma unroll
    for (int n = 0; n < NF; ++n) acc[m][n] = (f32x4){0.f, 0.f, 0.f, 0.f};

  auto stA = [&](int buf, int half, int k0) {
#pragma unroll
    for (int i = 0; i < 2; ++i) {
      const int c = half * (BM / 16) + wid * 2 + i;
      __builtin_amdgcn_global_load_lds(
          (const AS1 void*)(Ab + (size_t)(c * 8 + lr) * DIM + k0 + lcs),
          (AS3 void*)(&As[buf][c * 512]), 16, 0, 0);
    }
  };
  auto stB = [&](int buf, int half, int k0) {
#pragma unroll
    for (int i = 0; i < 2; ++i) {
      const int c = half * (BN / 16) + wid * 2 + i;
      __builtin_amdgcn_global_load_lds(
          (const AS1 void*)(Bb + (size_t)(c * 8 + lr) * DIM + k0 + lcs),
          (AS3 void*)(&Bs[buf][c * 512]), 16, 0, 0);
    }
  };

  stA(0, 0, 0); stA(0, 1, 0);
  stB(0, 0, 0); stB(0, 1, 0);
  stB(1, 0, 64); stB(1, 1, 64);
  asm volatile("s_waitcnt vmcnt(4)" ::: "memory");
  bar();

  for (int t = 0; t < NT; ++t) {
    const int buf = t & 1;
    const int k0 = t * 64;
    bf16x8 bfrag[NF][2];
#pragma unroll
    for (int p = 0; p < 4; ++p) {
      if (p == 0) {
#pragma unroll
        for (int n = 0; n < NF; ++n)
#pragma unroll
          for (int ks = 0; ks < 2; ++ks) {
            const int r = wc * RN + n * 16 + c15;
            bfrag[n][ks] = *(const bf16x8*)(
                &Bs[buf][r * 64 + ((ks * 32 + g * 8) ^ ((r & 7) << 3))]);
          }
      }
      bf16x8 af[MPH][2];
#pragma unroll
      for (int m = 0; m < MPH; ++m)
#pragma unroll
        for (int ks = 0; ks < 2; ++ks) {
          const int r = wr * RM + (p * MPH + m) * 16 + c15;
          af[m][ks] = *(const bf16x8*)(
              &As[buf][r * 64 + ((ks * 32 + g * 8) ^ ((r & 7) << 3))]);
        }
      if (p == 0) {
        if (t + 1 < NT) stA(buf ^ 1, 0, k0 + 64);
      } else if (p == 1) {
        if (t + 1 < NT) stA(buf ^ 1, 1, k0 + 64);
      } else if (p == 2) {
        if (t + 2 < NT) stB(buf, 0, k0 + 128);
      } else {
        if (t + 2 < NT) stB(buf, 1, k0 + 128);
        if (t < NT - 2) asm volatile("s_waitcnt vmcnt(4)" ::: "memory");
        else            asm volatile("s_waitcnt vmcnt(0)" ::: "memory");
      }
      bar();
      __builtin_amdgcn_s_setprio(1);
#pragma unroll
      for (int m = 0; m < MPH; ++m)
#pragma unroll
        for (int n = 0; n < NF; ++n)
#pragma unroll
          for (int ks = 0; ks < 2; ++ks)
            acc[p * MPH + m][n] = __builtin_amdgcn_mfma_f32_16x16x32_bf16(
                af[m][ks], bfrag[n][ks], acc[p * MPH + m][n], 0, 0, 0);
      __builtin_amdgcn_s_setprio(0);
      bar();
    }
  }

#pragma unroll
  for (int m = 0; m < MF; ++m) {
    const int row0 = bm * BM + wr * RM + m * 16 + g * 4;
#pragma unroll
    for (int n = 0; n < NF; ++n) {
      const int col = nb * BN + wc * RN + n * 16 + c15;
#pragma unroll
      for (int j = 0; j < 4; ++j) {
        const size_t idx = (size_t)(row0 + j) * DIM + col;
        if constexpr (sizeof(OUT_T) == 2) Cmat[idx] = f2bf(acc[m][n][j]);
        else Cmat[idx] = acc[m][n][j];
      }
    }
  }
}

// ---------------- sparse flash attention, fixed-base softmax -----------------
// No online max (logits bounded ~|8|; f32 exp overflows only past 88):
// p = exp(s), per-lane l partials, one shuffle-reduce at end.
// 64-key tiles; k=0 global column handled as a writeout fixup for klo>0.
__global__ __launch_bounds__(256) void sparse_attn(
    const u16* __restrict__ Q, const u16* __restrict__ K,
    const u16* __restrict__ V, u16* __restrict__ AO) {
  __shared__ u16 Ks[64 * 72];      // [key][hd] pitch 72
  __shared__ u16 Vt[64 * 72];      // [hd][key^swz] pitch 72
  __shared__ u16 Pl[4][16 * 72];   // per-wave P [16 q][64 key]
  __shared__ float Pg[4][16];      // global-col fixup transpose

  const int tid = threadIdx.x;
  const int lane = tid & 63;
  const int wid = tid >> 6;
  const int c15 = lane & 15;
  const int g = lane >> 4;
  const int q0 = blockIdx.x * 64;
  const size_t hb = (size_t)blockIdx.z * T_SEQ * DIM + (size_t)blockIdx.y * HDIM;

  bf16x8 qf0, qf1;
  {
    const u16* qp = Q + hb + (size_t)(q0 + wid * 16 + c15) * DIM + g * 8;
    qf0 = *(const bf16x8*)qp;
    qf1 = *(const bf16x8*)(qp + 32);
  }

  float lrun[4] = {0.f, 0.f, 0.f, 0.f};
  f32x4 ao[4];
#pragma unroll
  for (int c = 0; c < 4; ++c) ao[c] = (f32x4){0.f, 0.f, 0.f, 0.f};

  const int klo = (q0 > WIN) ? (q0 - WIN) : 0;
  int khi = q0 + 64 + WIN;
  if (khi > T_SEQ) khi = T_SEQ;
  const int nt = (khi - klo) >> 6;   // 3..5 (all bounds are multiples of 64)

  const int srr = tid >> 2;                    // key row 0..63
  const int scc = (tid & 3) * 16;              // hd col base
  const int vrow = srr ^ (scc & 16 ? 16 : 0) ^ (scc & 32 ? 32 : 0);
  // vrow = srr ^ ((scc>>4)<<4): spreads the 4 col-groups across banks
  const int vr = srr ^ ((scc >> 4) << 4);

  const u16* kbase = K + hb + (size_t)(klo + srr) * DIM + scc;
  const u16* vbase = V + hb + (size_t)(klo + srr) * DIM + scc;
  u16x8 kp0 = *(const u16x8*)kbase;
  u16x8 kp1 = *(const u16x8*)(kbase + 8);
  u16x8 vp0 = *(const u16x8*)vbase;
  u16x8 vp1 = *(const u16x8*)(vbase + 8);

  for (int ti = 0; ti < nt; ++ti) {
    const int kt = klo + ti * 64;
    *(u16x8*)(Ks + srr * 72 + scc) = kp0;
    *(u16x8*)(Ks + srr * 72 + scc + 8) = kp1;
#pragma unroll
    for (int e = 0; e < 8; ++e) {
      Vt[(scc + e) * 72 + vr] = vp0[e];
      Vt[(scc + 8 + e) * 72 + vr] = vp1[e];
    }
    __syncthreads();

    if (ti + 1 < nt) {
      const u16* kn = kbase + (size_t)(ti + 1) * 64 * DIM;
      const u16* vn = vbase + (size_t)(ti + 1) * 64 * DIM;
      kp0 = *(const u16x8*)kn;
      kp1 = *(const u16x8*)(kn + 8);
      vp0 = *(const u16x8*)vn;
      vp1 = *(const u16x8*)(vn + 8);
    }

    // ---- S = Q K^T (four 16-key groups) ----
    f32x4 s[4];
#pragma unroll
    for (int t = 0; t < 4; ++t) {
      const u16* kr = Ks + (t * 16 + c15) * 72 + g * 8;
      bf16x8 ka = *(const bf16x8*)kr;
      bf16x8 kb = *(const bf16x8*)(kr + 32);
      s[t] = (f32x4){0.f, 0.f, 0.f, 0.f};
      s[t] = __builtin_amdgcn_mfma_f32_16x16x32_bf16(qf0, ka, s[t], 0, 0, 0);
      s[t] = __builtin_amdgcn_mfma_f32_16x16x32_bf16(qf1, kb, s[t], 0, 0, 0);
    }
    // ---- masked exp (no max), P write, l accumulate ----
#pragma unroll
    for (int j = 0; j < 4; ++j) {
      const int qg = q0 + wid * 16 + g * 4 + j;
#pragma unroll
      for (int t = 0; t < 4; ++t) {
        const int kg = kt + t * 16 + c15;
        const int dd = qg - kg;
        const bool ok = (kg == 0) || (dd <= WIN && dd >= -WIN);
        const float p = ok ? __expf(s[t][j] * 0.125f) : 0.f;
        lrun[j] += p;
        Pl[wid][(g * 4 + j) * 72 + t * 16 + c15] = f2bf(p);
      }
    }
    asm volatile("s_waitcnt lgkmcnt(0)" ::: "memory");

    // ---- O += P @ V ----
    const bf16x8 pa0 = *(const bf16x8*)(&Pl[wid][c15 * 72 + g * 8]);
    const bf16x8 pa1 = *(const bf16x8*)(&Pl[wid][c15 * 72 + 32 + g * 8]);
#pragma unroll
    for (int c = 0; c < 4; ++c) {
      const int rb = (c * 16 + c15) * 72;
      bf16x8 va = *(const bf16x8*)(Vt + rb + ((g * 8) ^ (c << 4)));
      bf16x8 vb = *(const bf16x8*)(Vt + rb + ((32 + g * 8) ^ (c << 4)));
      ao[c] = __builtin_amdgcn_mfma_f32_16x16x32_bf16(pa0, va, ao[c], 0, 0, 0);
      ao[c] = __builtin_amdgcn_mfma_f32_16x16x32_bf16(pa1, vb, ao[c], 0, 0, 0);
    }
    __syncthreads();
  }

  // ---- l reduce across the 16 key-lanes ----
  float ltot[4];
#pragma unroll
  for (int j = 0; j < 4; ++j) {
    float ls = lrun[j];
    ls += __shfl_xor(ls, 1);
    ls += __shfl_xor(ls, 2);
    ls += __shfl_xor(ls, 4);
    ls += __shfl_xor(ls, 8);
    ltot[j] = ls;
  }

  // ---- k=0 global-column fixup (only when the main loop skipped it) ----
  if (klo > 0) {
    const u16x8 qu0 = *(const u16x8*)&qf0;
    const u16x8 qu1 = *(const u16x8*)&qf1;
    const u16x8 k0a = *(const u16x8*)(K + hb + g * 8);
    const u16x8 k0b = *(const u16x8*)(K + hb + 32 + g * 8);
    float sg = 0.f;
#pragma unroll
    for (int e = 0; e < 8; ++e)
      sg += bf2f(qu0[e]) * bf2f(k0a[e]) + bf2f(qu1[e]) * bf2f(k0b[e]);
    sg += __shfl_xor(sg, 16);
    sg += __shfl_xor(sg, 32);                // all lanes: full dot for row c15
    const float pg = __expf(sg * 0.125f);
    Pg[wid][c15] = pg;
    asm volatile("s_waitcnt lgkmcnt(0)" ::: "memory");
#pragma unroll
    for (int j = 0; j < 4; ++j) {
      const float pj = Pg[wid][g * 4 + j];
      ltot[j] += pj;
#pragma unroll
      for (int c = 0; c < 4; ++c)
        ao[c][j] += pj * bf2f(V[hb + c * 16 + c15]);
    }
  }

  // ---- writeout ----
#pragma unroll
  for (int j = 0; j < 4; ++j) {
    const int qrow = q0 + wid * 16 + g * 4 + j;
    const float inv = 1.0f / ltot[j];
#pragma unroll
    for (int c = 0; c < 4; ++c)
      AO[hb + (size_t)qrow * DIM + c * 16 + c15] = f2bf(ao[c][j] * inv);
  }
  (void)vrow;
}

// ---------------- global row (row 0 attends everything) ----------------------
__global__ __launch_bounds__(256) void global_row_attn(
    const u16* __restrict__ Q, const u16* __restrict__ K,
    const u16* __restrict__ V, u16* __restrict__ AO) {
  __shared__ float qs[HDIM];
  __shared__ float ps[T_SEQ];
  __shared__ float redm[4], reds[4];
  __shared__ float outp[4][HDIM];

  const int tid = threadIdx.x;
  const int lane = tid & 63;
  const int wv = tid >> 6;
  const size_t hb = (size_t)(blockIdx.x >> 4) * T_SEQ * DIM +
                    (size_t)(blockIdx.x & 15) * HDIM;

  if (tid < HDIM) qs[tid] = bf2f(Q[hb + tid]);
  __syncthreads();

  float lg[8];
  float lmax = -1e30f;
#pragma unroll
  for (int j = 0; j < 8; ++j) {
    const u16* kr = K + hb + (size_t)(tid + 256 * j) * DIM;
    float acc = 0.f;
#pragma unroll
    for (int d0 = 0; d0 < 8; ++d0) {
      u16x8 kv = *(const u16x8*)(kr + d0 * 8);
#pragma unroll
      for (int e = 0; e < 8; ++e) acc += qs[d0 * 8 + e] * bf2f(kv[e]);
    }
    lg[j] = acc * 0.125f;
    lmax = fmaxf(lmax, lg[j]);
  }
#pragma unroll
  for (int s = 1; s < 64; s <<= 1) lmax = fmaxf(lmax, __shfl_xor(lmax, s));
  if (lane == 0) redm[wv] = lmax;
  __syncthreads();
  const float bmax = fmaxf(fmaxf(redm[0], redm[1]), fmaxf(redm[2], redm[3]));

  float lsum = 0.f;
#pragma unroll
  for (int j = 0; j < 8; ++j) {
    const float p = __expf(lg[j] - bmax);
    ps[tid + 256 * j] = p;
    lsum += p;
  }
#pragma unroll
  for (int s = 1; s < 64; s <<= 1) lsum += __shfl_xor(lsum, s);
  if (lane == 0) reds[wv] = lsum;
  __syncthreads();
  const float denom = reds[0] + reds[1] + reds[2] + reds[3];

  const int d = tid & 63;
  float acc = 0.f;
#pragma unroll 8
  for (int k = wv * 512; k < wv * 512 + 512; ++k)
    acc += ps[k] * bf2f(V[hb + (size_t)k * DIM + d]);
  outp[wv][d] = acc;
  __syncthreads();
  if (tid < HDIM) {
    const float tot = outp[0][tid] + outp[1][tid] + outp[2][tid] + outp[3][tid];
    AO[hb + tid] = f2bf(tot / denom);
  }
}

// ---------------- launch -----------------------------------------------------
extern "C" void kernel_launch(void* const* d_in, const int* in_sizes, int n_in,
                              void* d_out, int out_size, void* d_ws, size_t ws_size,
                              hipStream_t stream) {
  const float* x  = (const float*)d_in[0];
  const float* Wq = (const float*)d_in[1];
  const float* Wk = (const float*)d_in[2];
  const float* Wv = (const float*)d_in[3];
  const float* Wo = (const float*)d_in[4];
  float* out = (float*)d_out;

  const int XN = 2 * T_SEQ * DIM;
  const int WN = DIM * DIM;

  u16* ws  = (u16*)d_ws;
  u16* xb  = ws;                 // bf16 x; reused as AO after QKV
  u16* Wqb = ws + (size_t)XN;
  u16* Wkb = Wqb + WN;
  u16* Wvb = Wkb + WN;
  u16* Wob = Wvb + WN;
  u16* Qb  = Wob + WN;
  u16* Kb  = Qb + (size_t)XN;
  u16* Vb  = Kb + (size_t)XN;

  cvt_bf16<<<XN / 8 / 256, 256, 0, stream>>>(x, xb, XN / 8);
  cvt_w4<<<dim3(WN / 8 / 256, 4), 256, 0, stream>>>(Wq, Wk, Wv, Wo,
                                                    Wqb, Wkb, Wvb, Wob);

  gemm3<256, 256, 2, 4, u16><<<192, 512, 0, stream>>>(
      xb, Wqb, Wkb, Wvb, Qb, Kb, Vb, 16);

  sparse_attn<<<dim3(T_SEQ / 64, 16, 2), 256, 0, stream>>>(Qb, Kb, Vb, xb);
  global_row_attn<<<32, 256, 0, stream>>>(Qb, Kb, Vb, xb);

  gemm3<128, 128, 2, 2, float><<<256, 256, 0, stream>>>(
      xb, Wob, Wob, Wob, out, out, out, 32);
}

// Round 6
// 128.360 us; speedup vs baseline: 2.9304x; 1.0914x over previous
//
#include <hip/hip_runtime.h>

typedef unsigned short u16;
typedef __attribute__((ext_vector_type(8))) __bf16 bf16x8;
typedef __attribute__((ext_vector_type(4))) float f32x4;
typedef __attribute__((ext_vector_type(8))) u16 u16x8;

#define T_SEQ 2048
#define DIM   1024
#define HDIM  64
#define WIN   128
#define QS    3072   // row stride of fused QKV buffer

#define AS1 __attribute__((address_space(1)))
#define AS3 __attribute__((address_space(3)))

__device__ __forceinline__ u16 f2bf(float f) {
  union { float f; unsigned u; } v; v.f = f;
  unsigned r = v.u + 0x7fffu + ((v.u >> 16) & 1u);  // RNE
  return (u16)(r >> 16);
}
__device__ __forceinline__ float bf2f(u16 u) {
  union { unsigned u; float f; } v; v.u = ((unsigned)u) << 16; return v.f;
}
__device__ __forceinline__ void bar() {
  asm volatile("" ::: "memory");
  __builtin_amdgcn_s_barrier();
  asm volatile("" ::: "memory");
}

// ---------------- fused fp32 -> bf16 convert (x + 4 weights) -----------------
// blocks 0..2047: x (4.2M elems). blocks 2048..4095: weights, 512 blocks each;
// Wq/Wk/Wv/Wo bf16 copies are CONTIGUOUS (wb) => QKV GEMM uses rows 0..3071.
__global__ __launch_bounds__(256) void cvt_all(
    const float* __restrict__ x,  const float* __restrict__ wq,
    const float* __restrict__ wk, const float* __restrict__ wv,
    const float* __restrict__ wo, u16* __restrict__ xb, u16* __restrict__ wb) {
  const int bid = blockIdx.x;
  const float* s;
  u16* d;
  int off;
  if (bid < 2048) {
    s = x; d = xb; off = bid * 2048;
  } else {
    const int w = bid - 2048;
    const int m = w >> 9;
    s = (m == 0) ? wq : ((m == 1) ? wk : ((m == 2) ? wv : wo));
    d = wb + ((size_t)m << 20);
    off = (w & 511) * 2048;
  }
  const int i = off + threadIdx.x * 8;
  const float4* s4 = (const float4*)(s + i);
  float4 a = s4[0], b = s4[1];
  u16x8 r;
  r[0] = f2bf(a.x); r[1] = f2bf(a.y); r[2] = f2bf(a.z); r[3] = f2bf(a.w);
  r[4] = f2bf(b.x); r[5] = f2bf(b.y); r[6] = f2bf(b.z); r[7] = f2bf(b.w);
  *(u16x8*)(d + i) = r;
}

// ---------------- C = A @ B^T, 4-phase pipelined + T2 swizzle ---------------
// A [M,1024], B [N,1024], C [M,N] with row stride OS. Grid = nbm * (N/BN).
// Per K-tile 4 phases: {ds_read frags; stage; [P3: counted vmcnt]; bar;
// setprio(1); MFMA; setprio(0); bar}. Stage ring: P0/P1 A-halves(t+1) ->
// As[buf^1]; P2 B(t+2) -> Bs[buf] (dead after P0's reg reads, barrier-
// separated). vmcnt(BNW) at P3 publishes tile t+1; only the tail drains to 0.
template <int BM, int BN, int WM, int WN, int OS, typename OUT_T>
__global__ __launch_bounds__(WM * WN * 64, 2) void gemm3(
    const u16* __restrict__ A, const u16* __restrict__ B,
    OUT_T* __restrict__ C, int nbm) {
  constexpr int NW = WM * WN;
  constexpr int RM = BM / WM, RN = BN / WN;
  constexpr int MF = RM / 16, NF = RN / 16;
  constexpr int MPH = MF / 4;
  constexpr int NT = DIM / 64;
  constexpr int CA = BM / 8, CB = BN / 8;
  constexpr int ANW = CA / NW;   // A chunks per wave per K-tile (4)
  constexpr int BNW = CB / NW;   // B chunks per wave per K-tile (3 or 4)

  __shared__ u16 As[2][BM * 64];
  __shared__ u16 Bs[2][BN * 64];

  const int tid = threadIdx.x;
  const int lane = tid & 63;
  const int wid = tid >> 6;
  const int wr = wid / WN, wc = wid % WN;
  const int c15 = lane & 15, g = lane >> 4;
  const int lr = lane >> 3;
  const int lcs = ((lane & 7) ^ lr) << 3;   // inverse-swizzled source col

  const int cpx = gridDim.x >> 3;           // bijective XCD swizzle (grid%8==0)
  const int bid = ((int)blockIdx.x & 7) * cpx + ((int)blockIdx.x >> 3);
  const int bm = bid % nbm;
  const int nb = bid / nbm;
  const u16* Ab = A + (size_t)bm * BM * DIM;
  const u16* Bb = B + (size_t)nb * BN * DIM;

  f32x4 acc[MF][NF];
#pragma unroll
  for (int m = 0; m < MF; ++m)
#pragma unroll
    for (int n = 0; n < NF; ++n) acc[m][n] = (f32x4){0.f, 0.f, 0.f, 0.f};

  auto stA = [&](int buf, int half, int k0) {
#pragma unroll
    for (int i = 0; i < ANW / 2; ++i) {
      const int c = half * (CA / 2) + wid * (ANW / 2) + i;
      __builtin_amdgcn_global_load_lds(
          (const AS1 void*)(Ab + (size_t)(c * 8 + lr) * DIM + k0 + lcs),
          (AS3 void*)(&As[buf][c * 512]), 16, 0, 0);
    }
  };
  auto stB = [&](int buf, int k0) {
#pragma unroll
    for (int i = 0; i < BNW; ++i) {
      const int c = wid * BNW + i;
      __builtin_amdgcn_global_load_lds(
          (const AS1 void*)(Bb + (size_t)(c * 8 + lr) * DIM + k0 + lcs),
          (AS3 void*)(&Bs[buf][c * 512]), 16, 0, 0);
    }
  };

  // prologue: A(0), B(0), B(1); keep B(1) in flight.
  stA(0, 0, 0); stA(0, 1, 0);
  stB(0, 0); stB(1, 64);
  if constexpr (BNW == 3) asm volatile("s_waitcnt vmcnt(3)" ::: "memory");
  else                    asm volatile("s_waitcnt vmcnt(4)" ::: "memory");
  bar();

  for (int t = 0; t < NT; ++t) {
    const int buf = t & 1;
    const int k0 = t * 64;
    bf16x8 bfrag[NF][2];
#pragma unroll
    for (int p = 0; p < 4; ++p) {
      if (p == 0) {
#pragma unroll
        for (int n = 0; n < NF; ++n)
#pragma unroll
          for (int ks = 0; ks < 2; ++ks) {
            const int r = wc * RN + n * 16 + c15;
            bfrag[n][ks] = *(const bf16x8*)(
                &Bs[buf][r * 64 + ((ks * 32 + g * 8) ^ ((r & 7) << 3))]);
          }
      }
      bf16x8 af[MPH][2];
#pragma unroll
      for (int m = 0; m < MPH; ++m)
#pragma unroll
        for (int ks = 0; ks < 2; ++ks) {
          const int r = wr * RM + (p * MPH + m) * 16 + c15;
          af[m][ks] = *(const bf16x8*)(
              &As[buf][r * 64 + ((ks * 32 + g * 8) ^ ((r & 7) << 3))]);
        }
      if (p == 0) {
        if (t + 1 < NT) stA(buf ^ 1, 0, k0 + 64);
      } else if (p == 1) {
        if (t + 1 < NT) stA(buf ^ 1, 1, k0 + 64);
      } else if (p == 2) {
        if (t + 2 < NT) stB(buf, k0 + 128);
      } else {
        if (t < NT - 2) {
          if constexpr (BNW == 3) asm volatile("s_waitcnt vmcnt(3)" ::: "memory");
          else                    asm volatile("s_waitcnt vmcnt(4)" ::: "memory");
        } else {
          asm volatile("s_waitcnt vmcnt(0)" ::: "memory");
        }
      }
      bar();
      __builtin_amdgcn_s_setprio(1);
#pragma unroll
      for (int m = 0; m < MPH; ++m)
#pragma unroll
        for (int n = 0; n < NF; ++n)
#pragma unroll
          for (int ks = 0; ks < 2; ++ks)
            acc[p * MPH + m][n] = __builtin_amdgcn_mfma_f32_16x16x32_bf16(
                af[m][ks], bfrag[n][ks], acc[p * MPH + m][n], 0, 0, 0);
      __builtin_amdgcn_s_setprio(0);
      bar();
    }
  }

  // epilogue: C/D layout col=lane&15, row=(lane>>4)*4+j
#pragma unroll
  for (int m = 0; m < MF; ++m) {
    const int row0 = bm * BM + wr * RM + m * 16 + g * 4;
#pragma unroll
    for (int n = 0; n < NF; ++n) {
      const int col = nb * BN + wc * RN + n * 16 + c15;
#pragma unroll
      for (int j = 0; j < 4; ++j) {
        const size_t idx = (size_t)(row0 + j) * OS + col;
        if constexpr (sizeof(OUT_T) == 2) C[idx] = f2bf(acc[m][n][j]);
        else C[idx] = acc[m][n][j];
      }
    }
  }
}

// ---------------- sparse flash attention + embedded global row ---------------
// QKV fused buffer [B*T, 3072]: Q cols 0..1023, K 1024.., V 2048..
// blockIdx.x < 32: windowed rows (fixed-base softmax, k=0 fixup).
// blockIdx.x == 32: full-range attention for row 0 (overwrites AO row 0;
// the q0==0 windowed block skips its qrow==0 write => disjoint).
__global__ __launch_bounds__(256) void sparse_attn(
    const u16* __restrict__ QKV, u16* __restrict__ AO) {
  __shared__ u16 Ks[64 * 72];
  __shared__ u16 Vt[64 * 72];
  __shared__ u16 Pl[4][16 * 72];
  __shared__ float Pg[4][16];

  const int tid = threadIdx.x;
  const int lane = tid & 63;
  const int wid = tid >> 6;
  const size_t hq = (size_t)blockIdx.z * T_SEQ * QS + (size_t)blockIdx.y * HDIM;
  const size_t ha = (size_t)blockIdx.z * T_SEQ * DIM + (size_t)blockIdx.y * HDIM;
  const u16* Qp = QKV + hq;
  const u16* Kp = QKV + hq + 1024;
  const u16* Vp = QKV + hq + 2048;

  if (blockIdx.x == 32) {
    // ---- global row 0 over all T keys ----
    float* qs   = (float*)Pg;        // 64 floats
    float* ps   = (float*)Ks;        // 2048 floats (8KB <= 9216B)
    float* redm = (float*)Pl;        // 4
    float* reds = redm + 4;          // 4
    float* outp = reds + 4;          // 4*64

    const int wv = wid;
    if (tid < HDIM) qs[tid] = bf2f(Qp[tid]);
    __syncthreads();

    float lg[8];
    float lmax = -1e30f;
#pragma unroll
    for (int j = 0; j < 8; ++j) {
      const u16* kr = Kp + (size_t)(tid + 256 * j) * QS;
      float acc = 0.f;
#pragma unroll
      for (int d0 = 0; d0 < 8; ++d0) {
        u16x8 kv = *(const u16x8*)(kr + d0 * 8);
#pragma unroll
        for (int e = 0; e < 8; ++e) acc += qs[d0 * 8 + e] * bf2f(kv[e]);
      }
      lg[j] = acc * 0.125f;
      lmax = fmaxf(lmax, lg[j]);
    }
#pragma unroll
    for (int s = 1; s < 64; s <<= 1) lmax = fmaxf(lmax, __shfl_xor(lmax, s));
    if (lane == 0) redm[wv] = lmax;
    __syncthreads();
    const float bmax = fmaxf(fmaxf(redm[0], redm[1]), fmaxf(redm[2], redm[3]));

    float lsum = 0.f;
#pragma unroll
    for (int j = 0; j < 8; ++j) {
      const float p = __expf(lg[j] - bmax);
      ps[tid + 256 * j] = p;
      lsum += p;
    }
#pragma unroll
    for (int s = 1; s < 64; s <<= 1) lsum += __shfl_xor(lsum, s);
    if (lane == 0) reds[wv] = lsum;
    __syncthreads();
    const float denom = reds[0] + reds[1] + reds[2] + reds[3];

    const int d = tid & 63;
    float acc = 0.f;
#pragma unroll 8
    for (int k = wv * 512; k < wv * 512 + 512; ++k)
      acc += ps[k] * bf2f(Vp[(size_t)k * QS + d]);
    outp[wv * 64 + d] = acc;
    __syncthreads();
    if (tid < HDIM) {
      const float tot = outp[tid] + outp[64 + tid] + outp[128 + tid] + outp[192 + tid];
      AO[ha + tid] = f2bf(tot / denom);
    }
    return;
  }

  // ---- windowed rows ----
  const int c15 = lane & 15;
  const int g = lane >> 4;
  const int q0 = blockIdx.x * 64;

  bf16x8 qf0, qf1;
  {
    const u16* qp = Qp + (size_t)(q0 + wid * 16 + c15) * QS + g * 8;
    qf0 = *(const bf16x8*)qp;
    qf1 = *(const bf16x8*)(qp + 32);
  }

  float lrun[4] = {0.f, 0.f, 0.f, 0.f};
  f32x4 ao[4];
#pragma unroll
  for (int c = 0; c < 4; ++c) ao[c] = (f32x4){0.f, 0.f, 0.f, 0.f};

  const int klo = (q0 > WIN) ? (q0 - WIN) : 0;
  int khi = q0 + 64 + WIN;
  if (khi > T_SEQ) khi = T_SEQ;
  const int nt = (khi - klo) >> 6;

  const int srr = tid >> 2;
  const int scc = (tid & 3) * 16;
  const int vr = srr ^ ((scc >> 4) << 4);

  const u16* kbase = Kp + (size_t)(klo + srr) * QS + scc;
  const u16* vbase = Vp + (size_t)(klo + srr) * QS + scc;
  u16x8 kp0 = *(const u16x8*)kbase;
  u16x8 kp1 = *(const u16x8*)(kbase + 8);
  u16x8 vp0 = *(const u16x8*)vbase;
  u16x8 vp1 = *(const u16x8*)(vbase + 8);

  for (int ti = 0; ti < nt; ++ti) {
    const int kt = klo + ti * 64;
    *(u16x8*)(Ks + srr * 72 + scc) = kp0;
    *(u16x8*)(Ks + srr * 72 + scc + 8) = kp1;
#pragma unroll
    for (int e = 0; e < 8; ++e) {
      Vt[(scc + e) * 72 + vr] = vp0[e];
      Vt[(scc + 8 + e) * 72 + vr] = vp1[e];
    }
    __syncthreads();

    if (ti + 1 < nt) {
      const u16* kn = kbase + (size_t)(ti + 1) * 64 * QS;
      const u16* vn = vbase + (size_t)(ti + 1) * 64 * QS;
      kp0 = *(const u16x8*)kn;
      kp1 = *(const u16x8*)(kn + 8);
      vp0 = *(const u16x8*)vn;
      vp1 = *(const u16x8*)(vn + 8);
    }

    f32x4 s[4];
#pragma unroll
    for (int t = 0; t < 4; ++t) {
      const u16* kr = Ks + (t * 16 + c15) * 72 + g * 8;
      bf16x8 ka = *(const bf16x8*)kr;
      bf16x8 kb = *(const bf16x8*)(kr + 32);
      s[t] = (f32x4){0.f, 0.f, 0.f, 0.f};
      s[t] = __builtin_amdgcn_mfma_f32_16x16x32_bf16(qf0, ka, s[t], 0, 0, 0);
      s[t] = __builtin_amdgcn_mfma_f32_16x16x32_bf16(qf1, kb, s[t], 0, 0, 0);
    }
#pragma unroll
    for (int j = 0; j < 4; ++j) {
      const int qg = q0 + wid * 16 + g * 4 + j;
#pragma unroll
      for (int t = 0; t < 4; ++t) {
        const int kg = kt + t * 16 + c15;
        const int dd = qg - kg;
        const bool ok = (kg == 0) || (dd <= WIN && dd >= -WIN);
        const float p = ok ? __expf(s[t][j] * 0.125f) : 0.f;
        lrun[j] += p;
        Pl[wid][(g * 4 + j) * 72 + t * 16 + c15] = f2bf(p);
      }
    }
    asm volatile("s_waitcnt lgkmcnt(0)" ::: "memory");

    const bf16x8 pa0 = *(const bf16x8*)(&Pl[wid][c15 * 72 + g * 8]);
    const bf16x8 pa1 = *(const bf16x8*)(&Pl[wid][c15 * 72 + 32 + g * 8]);
#pragma unroll
    for (int c = 0; c < 4; ++c) {
      const int rb = (c * 16 + c15) * 72;
      bf16x8 va = *(const bf16x8*)(Vt + rb + ((g * 8) ^ (c << 4)));
      bf16x8 vb = *(const bf16x8*)(Vt + rb + ((32 + g * 8) ^ (c << 4)));
      ao[c] = __builtin_amdgcn_mfma_f32_16x16x32_bf16(pa0, va, ao[c], 0, 0, 0);
      ao[c] = __builtin_amdgcn_mfma_f32_16x16x32_bf16(pa1, vb, ao[c], 0, 0, 0);
    }
    __syncthreads();
  }

  float ltot[4];
#pragma unroll
  for (int j = 0; j < 4; ++j) {
    float ls = lrun[j];
    ls += __shfl_xor(ls, 1);
    ls += __shfl_xor(ls, 2);
    ls += __shfl_xor(ls, 4);
    ls += __shfl_xor(ls, 8);
    ltot[j] = ls;
  }

  if (klo > 0) {
    const u16x8 qu0 = *(const u16x8*)&qf0;
    const u16x8 qu1 = *(const u16x8*)&qf1;
    const u16x8 k0a = *(const u16x8*)(Kp + g * 8);
    const u16x8 k0b = *(const u16x8*)(Kp + 32 + g * 8);
    float sg = 0.f;
#pragma unroll
    for (int e = 0; e < 8; ++e)
      sg += bf2f(qu0[e]) * bf2f(k0a[e]) + bf2f(qu1[e]) * bf2f(k0b[e]);
    sg += __shfl_xor(sg, 16);
    sg += __shfl_xor(sg, 32);
    const float pg = __expf(sg * 0.125f);
    Pg[wid][c15] = pg;
    asm volatile("s_waitcnt lgkmcnt(0)" ::: "memory");
#pragma unroll
    for (int j = 0; j < 4; ++j) {
      const float pj = Pg[wid][g * 4 + j];
      ltot[j] += pj;
#pragma unroll
      for (int c = 0; c < 4; ++c)
        ao[c][j] += pj * bf2f(Vp[c * 16 + c15]);
    }
  }

#pragma unroll
  for (int j = 0; j < 4; ++j) {
    const int qrow = q0 + wid * 16 + g * 4 + j;
    if (qrow == 0) continue;   // handled by the global-row block
    const float inv = 1.0f / ltot[j];
#pragma unroll
    for (int c = 0; c < 4; ++c)
      AO[ha + (size_t)qrow * DIM + c * 16 + c15] = f2bf(ao[c][j] * inv);
  }
}

// ---------------- launch -----------------------------------------------------
extern "C" void kernel_launch(void* const* d_in, const int* in_sizes, int n_in,
                              void* d_out, int out_size, void* d_ws, size_t ws_size,
                              hipStream_t stream) {
  const float* x  = (const float*)d_in[0];
  const float* Wq = (const float*)d_in[1];
  const float* Wk = (const float*)d_in[2];
  const float* Wv = (const float*)d_in[3];
  const float* Wo = (const float*)d_in[4];
  float* out = (float*)d_out;

  const int XN = 2 * T_SEQ * DIM;   // 4.19M
  const int WN = DIM * DIM;         // 1.05M

  u16* ws  = (u16*)d_ws;
  u16* xb  = ws;                    // bf16 x [4096,1024]; reused as AO
  u16* wb  = ws + (size_t)XN;       // Wq,Wk,Wv,Wo bf16, contiguous [4096,1024]
  u16* Wob = wb + (size_t)3 * WN;
  u16* qkv = wb + (size_t)4 * WN;   // [4096,3072]

  cvt_all<<<4096, 256, 0, stream>>>(x, Wq, Wk, Wv, Wo, xb, wb);

  // fused QKV: 256x192 tiles, grid 16*16 = 256 (1 block/CU, full coverage)
  gemm3<256, 192, 2, 4, QS, u16><<<256, 512, 0, stream>>>(xb, wb, qkv, 16);

  // windowed attention + embedded global-row blocks
  sparse_attn<<<dim3(33, 16, 2), 256, 0, stream>>>(qkv, xb);

  // output projection: 128x128 tiles, grid 32*8 = 256
  gemm3<128, 128, 2, 2, DIM, float><<<256, 256, 0, stream>>>(xb, Wob, out, 32);
}

// Round 7
// 106.637 us; speedup vs baseline: 3.5274x; 1.2037x over previous
//
#include <hip/hip_runtime.h>

typedef unsigned short u16;
typedef __attribute__((ext_vector_type(8))) __bf16 bf16x8;
typedef __attribute__((ext_vector_type(4))) float f32x4;
typedef __attribute__((ext_vector_type(8))) u16 u16x8;

#define T_SEQ 2048
#define DIM   1024
#define HDIM  64
#define WIN   128
#define XN_EL (2 * T_SEQ * DIM)   // 4194304

#define AS1 __attribute__((address_space(1)))
#define AS3 __attribute__((address_space(3)))

__device__ __forceinline__ u16 f2bf(float f) {
  union { float f; unsigned u; } v; v.f = f;
  unsigned r = v.u + 0x7fffu + ((v.u >> 16) & 1u);  // RNE
  return (u16)(r >> 16);
}
__device__ __forceinline__ float bf2f(u16 u) {
  union { unsigned u; float f; } v; v.u = ((unsigned)u) << 16; return v.f;
}
__device__ __forceinline__ void bar() {
  asm volatile("" ::: "memory");
  __builtin_amdgcn_s_barrier();
  asm volatile("" ::: "memory");
}

// ---------------- fused fp32 -> bf16 convert (x + 4 weights) -----------------
__global__ __launch_bounds__(256) void cvt_all(
    const float* __restrict__ x,  const float* __restrict__ wq,
    const float* __restrict__ wk, const float* __restrict__ wv,
    const float* __restrict__ wo, u16* __restrict__ xb, u16* __restrict__ wb) {
  const int bid = blockIdx.x;
  const float* s;
  u16* d;
  int off;
  if (bid < 2048) {
    s = x; d = xb; off = bid * 2048;
  } else {
    const int w = bid - 2048;
    const int m = w >> 9;
    s = (m == 0) ? wq : ((m == 1) ? wk : ((m == 2) ? wv : wo));
    d = wb + ((size_t)m << 20);
    off = (w & 511) * 2048;
  }
  const int i = off + threadIdx.x * 8;
  const float4* s4 = (const float4*)(s + i);
  float4 a = s4[0], b = s4[1];
  u16x8 r;
  r[0] = f2bf(a.x); r[1] = f2bf(a.y); r[2] = f2bf(a.z); r[3] = f2bf(a.w);
  r[4] = f2bf(b.x); r[5] = f2bf(b.y); r[6] = f2bf(b.z); r[7] = f2bf(b.w);
  *(u16x8*)(d + i) = r;
}

// ---------------- C = A @ B^T, 4-phase pipelined + T2 swizzle ---------------
// SPLIT=1: B is the concatenated [3072,1024] weights; C points at Q-buffer,
// columns scatter to {Q, Q+XN_EL, Q+2*XN_EL} by col>>10 (row stride DIM).
template <int BM, int BN, int WM, int WN, int OS, int SPLIT, typename OUT_T>
__global__ __launch_bounds__(WM * WN * 64, 2) void gemm3(
    const u16* __restrict__ A, const u16* __restrict__ B,
    OUT_T* __restrict__ C, int nbm) {
  constexpr int NW = WM * WN;
  constexpr int RM = BM / WM, RN = BN / WN;
  constexpr int MF = RM / 16, NF = RN / 16;
  constexpr int MPH = MF / 4;
  constexpr int NT = DIM / 64;
  constexpr int CA = BM / 8, CB = BN / 8;
  constexpr int ANW = CA / NW;
  constexpr int BNW = CB / NW;

  __shared__ u16 As[2][BM * 64];
  __shared__ u16 Bs[2][BN * 64];

  const int tid = threadIdx.x;
  const int lane = tid & 63;
  const int wid = tid >> 6;
  const int wr = wid / WN, wc = wid % WN;
  const int c15 = lane & 15, g = lane >> 4;
  const int lr = lane >> 3;
  const int lcs = ((lane & 7) ^ lr) << 3;

  const int cpx = gridDim.x >> 3;
  const int bid = ((int)blockIdx.x & 7) * cpx + ((int)blockIdx.x >> 3);
  const int bm = bid % nbm;
  const int nb = bid / nbm;
  const u16* Ab = A + (size_t)bm * BM * DIM;
  const u16* Bb = B + (size_t)nb * BN * DIM;

  f32x4 acc[MF][NF];
#pragma unroll
  for (int m = 0; m < MF; ++m)
#pragma unroll
    for (int n = 0; n < NF; ++n) acc[m][n] = (f32x4){0.f, 0.f, 0.f, 0.f};

  auto stA = [&](int buf, int half, int k0) {
#pragma unroll
    for (int i = 0; i < ANW / 2; ++i) {
      const int c = half * (CA / 2) + wid * (ANW / 2) + i;
      __builtin_amdgcn_global_load_lds(
          (const AS1 void*)(Ab + (size_t)(c * 8 + lr) * DIM + k0 + lcs),
          (AS3 void*)(&As[buf][c * 512]), 16, 0, 0);
    }
  };
  auto stB = [&](int buf, int k0) {
#pragma unroll
    for (int i = 0; i < BNW; ++i) {
      const int c = wid * BNW + i;
      __builtin_amdgcn_global_load_lds(
          (const AS1 void*)(Bb + (size_t)(c * 8 + lr) * DIM + k0 + lcs),
          (AS3 void*)(&Bs[buf][c * 512]), 16, 0, 0);
    }
  };

  stA(0, 0, 0); stA(0, 1, 0);
  stB(0, 0); stB(1, 64);
  if constexpr (BNW == 3) asm volatile("s_waitcnt vmcnt(3)" ::: "memory");
  else                    asm volatile("s_waitcnt vmcnt(4)" ::: "memory");
  bar();

  for (int t = 0; t < NT; ++t) {
    const int buf = t & 1;
    const int k0 = t * 64;
    bf16x8 bfrag[NF][2];
#pragma unroll
    for (int p = 0; p < 4; ++p) {
      if (p == 0) {
#pragma unroll
        for (int n = 0; n < NF; ++n)
#pragma unroll
          for (int ks = 0; ks < 2; ++ks) {
            const int r = wc * RN + n * 16 + c15;
            bfrag[n][ks] = *(const bf16x8*)(
                &Bs[buf][r * 64 + ((ks * 32 + g * 8) ^ ((r & 7) << 3))]);
          }
      }
      bf16x8 af[MPH][2];
#pragma unroll
      for (int m = 0; m < MPH; ++m)
#pragma unroll
        for (int ks = 0; ks < 2; ++ks) {
          const int r = wr * RM + (p * MPH + m) * 16 + c15;
          af[m][ks] = *(const bf16x8*)(
              &As[buf][r * 64 + ((ks * 32 + g * 8) ^ ((r & 7) << 3))]);
        }
      if (p == 0) {
        if (t + 1 < NT) stA(buf ^ 1, 0, k0 + 64);
      } else if (p == 1) {
        if (t + 1 < NT) stA(buf ^ 1, 1, k0 + 64);
      } else if (p == 2) {
        if (t + 2 < NT) stB(buf, k0 + 128);
      } else {
        if (t < NT - 2) {
          if constexpr (BNW == 3) asm volatile("s_waitcnt vmcnt(3)" ::: "memory");
          else                    asm volatile("s_waitcnt vmcnt(4)" ::: "memory");
        } else {
          asm volatile("s_waitcnt vmcnt(0)" ::: "memory");
        }
      }
      bar();
      __builtin_amdgcn_s_setprio(1);
#pragma unroll
      for (int m = 0; m < MPH; ++m)
#pragma unroll
        for (int n = 0; n < NF; ++n)
#pragma unroll
          for (int ks = 0; ks < 2; ++ks)
            acc[p * MPH + m][n] = __builtin_amdgcn_mfma_f32_16x16x32_bf16(
                af[m][ks], bfrag[n][ks], acc[p * MPH + m][n], 0, 0, 0);
      __builtin_amdgcn_s_setprio(0);
      bar();
    }
  }

  // epilogue: C/D layout col=lane&15, row=(lane>>4)*4+j
#pragma unroll
  for (int m = 0; m < MF; ++m) {
    const int row0 = bm * BM + wr * RM + m * 16 + g * 4;
#pragma unroll
    for (int n = 0; n < NF; ++n) {
      const int col = nb * BN + wc * RN + n * 16 + c15;
#pragma unroll
      for (int j = 0; j < 4; ++j) {
        if constexpr (SPLIT) {
          u16* dst = (u16*)C + (size_t)(col >> 10) * (size_t)XN_EL +
                     (col & 1023) + (size_t)(row0 + j) * DIM;
          *dst = f2bf(acc[m][n][j]);
        } else {
          const size_t idx = (size_t)(row0 + j) * OS + col;
          if constexpr (sizeof(OUT_T) == 2) C[idx] = f2bf(acc[m][n][j]);
          else C[idx] = acc[m][n][j];
        }
      }
    }
  }
}

// ---------------- sparse flash attention + embedded global row ---------------
// blockIdx.x < 32: windowed rows (fixed-base softmax, k=0 fixup).
// blockIdx.x == 32: full-range row 0, vectorized (overwrites AO row 0;
// the q0==0 windowed block skips its qrow==0 write => disjoint).
__global__ __launch_bounds__(256) void sparse_attn(
    const u16* __restrict__ Q, const u16* __restrict__ K,
    const u16* __restrict__ V, u16* __restrict__ AO) {
  __shared__ u16 Ks[64 * 72];
  __shared__ u16 Vt[64 * 72];
  __shared__ u16 Pl[4][16 * 72];
  __shared__ float Pg[4][16];

  const int tid = threadIdx.x;
  const int lane = tid & 63;
  const int wid = tid >> 6;
  const size_t ha = (size_t)blockIdx.z * T_SEQ * DIM + (size_t)blockIdx.y * HDIM;
  const u16* Qp = Q + ha;
  const u16* Kp = K + ha;
  const u16* Vp = V + ha;

  if (blockIdx.x == 32) {
    // ---- global row 0 over all T keys (fixed-base softmax, vectorized) ----
    float* qs   = (float*)Pg;        // 64 floats (256B)
    float* ps   = (float*)Ks;        // 2048 floats (8KB <= 9216B)
    float* rbuf = (float*)Vt;        // 32*64 floats (8KB <= 9216B)
    float* red  = (float*)Pl;        // 4 floats

    if (tid < HDIM) qs[tid] = bf2f(Qp[tid]);
    __syncthreads();

    float lsum = 0.f;
#pragma unroll
    for (int j = 0; j < 8; ++j) {
      const int k = tid + 256 * j;
      const u16* kr = Kp + (size_t)k * DIM;
      float acc = 0.f;
#pragma unroll
      for (int d0 = 0; d0 < 8; ++d0) {
        u16x8 kv = *(const u16x8*)(kr + d0 * 8);
#pragma unroll
        for (int e = 0; e < 8; ++e) acc += qs[d0 * 8 + e] * bf2f(kv[e]);
      }
      const float p = __expf(acc * 0.125f);
      ps[k] = p;
      lsum += p;
    }
#pragma unroll
    for (int s = 1; s < 64; s <<= 1) lsum += __shfl_xor(lsum, s);
    if (lane == 0) red[wid] = lsum;
    __syncthreads();
    const float denom = red[0] + red[1] + red[2] + red[3];

    // PV: thread (kg,dg) accumulates 8 d's over 64 keys, vectorized V loads
    const int kg = tid >> 3, dg = tid & 7;
    float facc[8] = {0.f, 0.f, 0.f, 0.f, 0.f, 0.f, 0.f, 0.f};
#pragma unroll 8
    for (int i = 0; i < 64; ++i) {
      const int k = kg * 64 + i;
      const u16x8 vv = *(const u16x8*)(Vp + (size_t)k * DIM + dg * 8);
      const float p = ps[k];
#pragma unroll
      for (int e = 0; e < 8; ++e) facc[e] += p * bf2f(vv[e]);
    }
#pragma unroll
    for (int e = 0; e < 8; ++e) rbuf[kg * 64 + dg * 8 + e] = facc[e];
    __syncthreads();
    if (tid < HDIM) {
      float tot = 0.f;
#pragma unroll
      for (int k2 = 0; k2 < 32; ++k2) tot += rbuf[k2 * 64 + tid];
      AO[ha + tid] = f2bf(tot / denom);
    }
    return;
  }

  // ---- windowed rows ----
  const int c15 = lane & 15;
  const int g = lane >> 4;
  const int q0 = blockIdx.x * 64;

  bf16x8 qf0, qf1;
  {
    const u16* qp = Qp + (size_t)(q0 + wid * 16 + c15) * DIM + g * 8;
    qf0 = *(const bf16x8*)qp;
    qf1 = *(const bf16x8*)(qp + 32);
  }

  float lrun[4] = {0.f, 0.f, 0.f, 0.f};
  f32x4 ao[4];
#pragma unroll
  for (int c = 0; c < 4; ++c) ao[c] = (f32x4){0.f, 0.f, 0.f, 0.f};

  const int klo = (q0 > WIN) ? (q0 - WIN) : 0;
  int khi = q0 + 64 + WIN;
  if (khi > T_SEQ) khi = T_SEQ;
  const int nt = (khi - klo) >> 6;

  const int srr = tid >> 2;
  const int scc = (tid & 3) * 16;
  const int vr = srr ^ ((scc >> 4) << 4);

  const u16* kbase = Kp + (size_t)(klo + srr) * DIM + scc;
  const u16* vbase = Vp + (size_t)(klo + srr) * DIM + scc;
  u16x8 kp0 = *(const u16x8*)kbase;
  u16x8 kp1 = *(const u16x8*)(kbase + 8);
  u16x8 vp0 = *(const u16x8*)vbase;
  u16x8 vp1 = *(const u16x8*)(vbase + 8);

  for (int ti = 0; ti < nt; ++ti) {
    const int kt = klo + ti * 64;
    *(u16x8*)(Ks + srr * 72 + scc) = kp0;
    *(u16x8*)(Ks + srr * 72 + scc + 8) = kp1;
#pragma unroll
    for (int e = 0; e < 8; ++e) {
      Vt[(scc + e) * 72 + vr] = vp0[e];
      Vt[(scc + 8 + e) * 72 + vr] = vp1[e];
    }
    __syncthreads();

    if (ti + 1 < nt) {
      const u16* kn = kbase + (size_t)(ti + 1) * 64 * DIM;
      const u16* vn = vbase + (size_t)(ti + 1) * 64 * DIM;
      kp0 = *(const u16x8*)kn;
      kp1 = *(const u16x8*)(kn + 8);
      vp0 = *(const u16x8*)vn;
      vp1 = *(const u16x8*)(vn + 8);
    }

    f32x4 s[4];
#pragma unroll
    for (int t = 0; t < 4; ++t) {
      const u16* kr = Ks + (t * 16 + c15) * 72 + g * 8;
      bf16x8 ka = *(const bf16x8*)kr;
      bf16x8 kb = *(const bf16x8*)(kr + 32);
      s[t] = (f32x4){0.f, 0.f, 0.f, 0.f};
      s[t] = __builtin_amdgcn_mfma_f32_16x16x32_bf16(qf0, ka, s[t], 0, 0, 0);
      s[t] = __builtin_amdgcn_mfma_f32_16x16x32_bf16(qf1, kb, s[t], 0, 0, 0);
    }
#pragma unroll
    for (int j = 0; j < 4; ++j) {
      const int qg = q0 + wid * 16 + g * 4 + j;
#pragma unroll
      for (int t = 0; t < 4; ++t) {
        const int kg = kt + t * 16 + c15;
        const int dd = qg - kg;
        const bool ok = (kg == 0) || (dd <= WIN && dd >= -WIN);
        const float p = ok ? __expf(s[t][j] * 0.125f) : 0.f;
        lrun[j] += p;
        Pl[wid][(g * 4 + j) * 72 + t * 16 + c15] = f2bf(p);
      }
    }
    asm volatile("s_waitcnt lgkmcnt(0)" ::: "memory");

    const bf16x8 pa0 = *(const bf16x8*)(&Pl[wid][c15 * 72 + g * 8]);
    const bf16x8 pa1 = *(const bf16x8*)(&Pl[wid][c15 * 72 + 32 + g * 8]);
#pragma unroll
    for (int c = 0; c < 4; ++c) {
      const int rb = (c * 16 + c15) * 72;
      bf16x8 va = *(const bf16x8*)(Vt + rb + ((g * 8) ^ (c << 4)));
      bf16x8 vb = *(const bf16x8*)(Vt + rb + ((32 + g * 8) ^ (c << 4)));
      ao[c] = __builtin_amdgcn_mfma_f32_16x16x32_bf16(pa0, va, ao[c], 0, 0, 0);
      ao[c] = __builtin_amdgcn_mfma_f32_16x16x32_bf16(pa1, vb, ao[c], 0, 0, 0);
    }
    __syncthreads();
  }

  float ltot[4];
#pragma unroll
  for (int j = 0; j < 4; ++j) {
    float ls = lrun[j];
    ls += __shfl_xor(ls, 1);
    ls += __shfl_xor(ls, 2);
    ls += __shfl_xor(ls, 4);
    ls += __shfl_xor(ls, 8);
    ltot[j] = ls;
  }

  if (klo > 0) {
    const u16x8 qu0 = *(const u16x8*)&qf0;
    const u16x8 qu1 = *(const u16x8*)&qf1;
    const u16x8 k0a = *(const u16x8*)(Kp + g * 8);
    const u16x8 k0b = *(const u16x8*)(Kp + 32 + g * 8);
    float sg = 0.f;
#pragma unroll
    for (int e = 0; e < 8; ++e)
      sg += bf2f(qu0[e]) * bf2f(k0a[e]) + bf2f(qu1[e]) * bf2f(k0b[e]);
    sg += __shfl_xor(sg, 16);
    sg += __shfl_xor(sg, 32);
    const float pg = __expf(sg * 0.125f);
    Pg[wid][c15] = pg;
    asm volatile("s_waitcnt lgkmcnt(0)" ::: "memory");
#pragma unroll
    for (int j = 0; j < 4; ++j) {
      const float pj = Pg[wid][g * 4 + j];
      ltot[j] += pj;
#pragma unroll
      for (int c = 0; c < 4; ++c)
        ao[c][j] += pj * bf2f(Vp[c * 16 + c15]);
    }
  }

#pragma unroll
  for (int j = 0; j < 4; ++j) {
    const int qrow = q0 + wid * 16 + g * 4 + j;
    if (qrow == 0) continue;   // handled by the global-row block
    const float inv = 1.0f / ltot[j];
#pragma unroll
    for (int c = 0; c < 4; ++c)
      AO[ha + (size_t)qrow * DIM + c * 16 + c15] = f2bf(ao[c][j] * inv);
  }
}

// ---------------- launch -----------------------------------------------------
extern "C" void kernel_launch(void* const* d_in, const int* in_sizes, int n_in,
                              void* d_out, int out_size, void* d_ws, size_t ws_size,
                              hipStream_t stream) {
  const float* x  = (const float*)d_in[0];
  const float* Wq = (const float*)d_in[1];
  const float* Wk = (const float*)d_in[2];
  const float* Wv = (const float*)d_in[3];
  const float* Wo = (const float*)d_in[4];
  float* out = (float*)d_out;

  const int WN = DIM * DIM;

  u16* ws  = (u16*)d_ws;
  u16* xb  = ws;                      // bf16 x [4096,1024]; reused as AO
  u16* wb  = ws + (size_t)XN_EL;      // Wq,Wk,Wv,Wo bf16 contiguous
  u16* Wob = wb + (size_t)3 * WN;
  u16* Qb  = wb + (size_t)4 * WN;     // [4096,1024]
  u16* Kb  = Qb + (size_t)XN_EL;
  u16* Vb  = Kb + (size_t)XN_EL;

  cvt_all<<<4096, 256, 0, stream>>>(x, Wq, Wk, Wv, Wo, xb, wb);

  // fused QKV: 256x192 tiles, grid 256; epilogue splits cols into Q/K/V
  gemm3<256, 192, 2, 4, DIM, 1, u16><<<256, 512, 0, stream>>>(xb, wb, Qb, 16);

  // windowed attention + embedded global-row blocks
  sparse_attn<<<dim3(33, 16, 2), 256, 0, stream>>>(Qb, Kb, Vb, xb);

  // output projection: 128x128 tiles, grid 256
  gemm3<128, 128, 2, 2, DIM, 0, float><<<256, 256, 0, stream>>>(xb, Wob, out, 32);
}